// Round 1
// baseline (786.954 us; speedup 1.0000x reference)
//
#include <hip/hip_runtime.h>
#include <math.h>

#define NN 8192
#define REV_CAP 64

// ---- ws layout (float element offsets) ----
static const size_t OFF_K     = 0;        // 405 floats (pad 512)
static const size_t OFF_STATS = 512;      // 96 floats (pad 640)
static const size_t OFF_CNT   = 640;      // int[8192]
static const size_t OFF_REV   = 8832;     // int[8192*64]
static const size_t OFF_X0    = 533120;   // 8192*32
static const size_t OFF_X1    = 795264;   // 8192*48
static const size_t OFF_X2    = 1188480;  // 8192*40
static const size_t OFF_Y0    = 1516160;  // 8192*32
static const size_t OFF_Y1    = 1778304;  // 8192*48
static const size_t OFF_Y2    = 2171520;  // 8192*40
static const size_t WS_FLOATS = 2499200;

// =================== K tensor init (device, double precision) ===================
__device__ double dfact(int n){ double r=1.0; for(int i=2;i<=n;++i) r*=(double)i; return r; }

__device__ double dcg(int j1,int m1,int j2,int m2,int j3,int m3){
  if (m1+m2!=m3) return 0.0;
  if (j3 < abs(j1-j2) || j3 > j1+j2) return 0.0;
  double pre = sqrt((double)(2*j3+1)*dfact(j3+j1-j2)*dfact(j3-j1+j2)*dfact(j1+j2-j3)/dfact(j1+j2+j3+1));
  pre *= sqrt(dfact(j3+m3)*dfact(j3-m3)*dfact(j1-m1)*dfact(j1+m1)*dfact(j2-m2)*dfact(j2+m2));
  double s=0.0;
  for(int k=0;k<=j1+j2-j3;++k){
    int d1=j1+j2-j3-k, d2=j1-m1-k, d3=j2+m2-k, d4=j3-j2+m1+k, d5=j3-j1-m2+k;
    if(d1<0||d2<0||d3<0||d4<0||d5<0) continue;
    double den = dfact(k)*dfact(d1)*dfact(d2)*dfact(d3)*dfact(d4)*dfact(d5);
    s += ((k&1)? -1.0: 1.0)/den;
  }
  return pre*s;
}

// Q(l)[r][c], complex, per reference _Q
__device__ void qentry(int l,int r,int c,double* re,double* im){
  const double s = 0.70710678118654752440;
  *re=0.0; *im=0.0;
  if (r==l){ if(c==l) *re=1.0; return; }
  if (r>l){ int m=r-l;
    if (c==l+m) *re = ((m&1)? -s : s);
    else if (c==l-m) *re = s;
  } else { int m=l-r;
    if (c==l+m) *im = ((m&1)? s : -s);   // -i*(-1)^m*s
    else if (c==l-m) *im = s;            // i*s
  }
}

__global__ void k_initK(float* __restrict__ Kbuf){
  int tid = blockIdx.x*blockDim.x + threadIdx.x;
  if (tid >= 405) return;
  const int sizes[9]={1,25,9,45,75,25,25,75,125};
  const int l1s[9]={0,0,1,1,1,2,2,2,2};
  const int l2s[9]={0,2,0,2,2,0,2,2,2};
  const int l3s[9]={0,2,1,1,2,2,0,1,2};
  int p=0, rem=tid;
  for(p=0;p<9;++p){ if(rem < sizes[p]) break; rem -= sizes[p]; }
  int l1=l1s[p], l2=l2s[p], l3=l3s[p];
  int n1=2*l1+1, n2=2*l2+1, n3=2*l3+1;
  int c = rem/(n1*n2); int r2 = rem%(n1*n2); int a=r2/n2; int b=r2%n2;
  (void)n3;
  double accRe=0, accIm=0;
  for(int C=0;C<2*l3+1;++C){
    double q3re,q3im; qentry(l3,c,C,&q3re,&q3im); q3im = -q3im; // conj
    if(q3re==0.0 && q3im==0.0) continue;
    for(int A=0;A<n1;++A){
      double q1re,q1im; qentry(l1,a,A,&q1re,&q1im);
      if(q1re==0.0 && q1im==0.0) continue;
      double pre_re = q3re*q1re - q3im*q1im;
      double pre_im = q3re*q1im + q3im*q1re;
      for(int B=0;B<n2;++B){
        double q2re,q2im; qentry(l2,b,B,&q2re,&q2im);
        if(q2re==0.0 && q2im==0.0) continue;
        double cgv = dcg(l1, A-l1, l2, B-l2, l3, C-l3);
        if (cgv==0.0) continue;
        accRe += (pre_re*q2re - pre_im*q2im)*cgv;
        accIm += (pre_re*q2im + pre_im*q2re)*cgv;
      }
    }
  }
  bool useImag = ((l1+l2+l3)&1)!=0;   // parity rule == reference's max|Im|>max|Re| test
  Kbuf[tid] = (float)(useImag? accIm : accRe);
}

// =================== x0 init ===================
__global__ void k_initx0(const float* __restrict__ W_emb, float* __restrict__ x0){
  int idx = blockIdx.x*256 + threadIdx.x;
  if (idx >= NN*32) return;
  x0[idx] = W_emb[idx & 31];
}

// =================== exact 9-NN (double) + reverse adjacency ===================
__global__ __launch_bounds__(256) void k_knn(const float* __restrict__ pos,
                                             int* __restrict__ cnt, int* __restrict__ rev){
  const int i = blockIdx.x;
  const int t = threadIdx.x;
  __shared__ double sd[256*9];
  __shared__ int    si[256*9];
  __shared__ double rd[256];
  __shared__ int    ri[256];
  const double pix = (double)pos[3*i], piy = (double)pos[3*i+1], piz = (double)pos[3*i+2];
  double d[9]; int id[9];
  #pragma unroll
  for(int k=0;k<9;++k){ d[k]=INFINITY; id[k]=0x7fffffff; }
  for(int cix=0;cix<32;++cix){
    int j = t + 256*cix;
    double dx = (double)pos[3*j]-pix, dy=(double)pos[3*j+1]-piy, dz=(double)pos[3*j+2]-piz;
    double d2 = dx*dx+dy*dy+dz*dz;
    if (d2 < d[8]) {
      d[8]=d2; id[8]=j;
      #pragma unroll
      for(int k=8;k>=1;--k){
        bool sw = (d[k]<d[k-1]) || (d[k]==d[k-1] && id[k]<id[k-1]);
        if(sw){ double td=d[k]; d[k]=d[k-1]; d[k-1]=td; int ti=id[k]; id[k]=id[k-1]; id[k-1]=ti; }
      }
    }
  }
  #pragma unroll
  for(int k=0;k<9;++k){ sd[t*9+k]=d[k]; si[t*9+k]=id[k]; }
  int ptr=0;
  __syncthreads();
  for(int r=0;r<9;++r){
    rd[t] = (ptr<9)? sd[t*9+ptr] : INFINITY;
    ri[t] = (ptr<9)? si[t*9+ptr] : 0x7fffffff;
    __syncthreads();
    for(int s=128;s>0;s>>=1){
      if(t<s){
        double od=rd[t+s]; int oi=ri[t+s];
        if (od<rd[t] || (od==rd[t] && oi<ri[t])) { rd[t]=od; ri[t]=oi; }
      }
      __syncthreads();
    }
    int w = ri[0];
    if (r>0 && t==0){            // r==0 is self
      int c = atomicAdd(&cnt[w],1);
      if (c < REV_CAP) rev[w*REV_CAP + c] = i;
    }
    if (t == (w & 255)) ptr++;   // owner thread advances its sorted list
    __syncthreads();
  }
}

// =================== message passing + aggregation + linear (one wave / dst node) ===================
__global__ __launch_bounds__(64) void k_msg(
  const float* __restrict__ pos,
  const int* __restrict__ cnt, const int* __restrict__ rev,
  const float* __restrict__ Kbuf,
  const float* __restrict__ x0, const float* __restrict__ x1, const float* __restrict__ x2,
  const float* __restrict__ tpw,
  const float* __restrict__ W0, const float* __restrict__ W1, const float* __restrict__ W2,
  float* __restrict__ y0, float* __restrict__ y1, float* __restrict__ y2)
{
  const int n = blockIdx.x;
  const int t = threadIdx.x;
  __shared__ float KL[405];
  __shared__ float BL[74];    // B2[5] B4[9] B5[15] B7[5] B8[15] B9[25]
  __shared__ float aL[480];   // a0[40] | a1[40*3] | a2[64*5]
  for(int q=t;q<405;q+=64) KL[q]=Kbuf[q];

  int u=0; float rw0=0.f,rw1=0.f,rw2=0.f,rw3=0.f;
  if(t<32){ u=t; rw0=tpw[u]; rw1=tpw[32+u]; }
  else if(t<48){ u=t-32; rw0=tpw[64+u]; rw1=tpw[80+u]; rw2=tpw[96+u]; }
  else if(t<56){ u=t-48; rw0=tpw[112+u]; rw1=tpw[120+u]; rw2=tpw[128+u]; rw3=tpw[136+u]; }
  __syncthreads();

  float acc[14];
  #pragma unroll
  for(int k=0;k<14;++k) acc[k]=0.f;

  const int deg0 = cnt[n];
  const int deg = (deg0 < REV_CAP)? deg0 : REV_CAP;
  const float pjx=pos[3*n], pjy=pos[3*n+1], pjz=pos[3*n+2];

  for(int e=0;e<deg;++e){
    const int i = rev[n*REV_CAP+e];
    const float ex = pjx - pos[3*i], ey = pjy - pos[3*i+1], ez = pjz - pos[3*i+2];
    const float rn = sqrtf(ex*ex+ey*ey+ez*ez) + 1e-12f;
    const float ux = ex/rn, uy = ey/rn, uz = ez/rn;
    float sh[5];
    const float s15 = 3.8729833462f, s5 = 2.2360679775f;
    sh[0]=s15*ux*uy; sh[1]=s15*uy*uz; sh[2]=0.5f*s5*(3.f*uz*uz-1.f);
    sh[3]=s15*ux*uz; sh[4]=0.5f*s15*(ux*ux-uy*uy);

    __syncthreads();  // WAR on BL from previous edge
    for(int q=t;q<74;q+=64){
      int base;
      if (q<5)       base = 1   + q*5;         // B2 <- K022
      else if (q<14) base = 35  + (q-5)*5;     // B4 <- K121
      else if (q<29) base = 80  + (q-14)*5;    // B5 <- K122
      else if (q<34) base = 180 + (q-29)*5;    // B7 <- K220
      else if (q<49) base = 205 + (q-34)*5;    // B8 <- K221
      else           base = 280 + (q-49)*5;    // B9 <- K222
      float bv=0.f;
      #pragma unroll
      for(int j=0;j<5;++j) bv += KL[base+j]*sh[j];
      BL[q]=bv;
    }
    __syncthreads();

    if (t<32){
      const float s0 = x0[i*32+u];
      acc[0] += rw0 * s0 * KL[0];                         // p1
      #pragma unroll
      for(int o=0;o<5;++o) acc[1+o] += rw1 * s0 * BL[o];  // p2
    } else if (t<48){
      float s1v[3];
      #pragma unroll
      for(int m=0;m<3;++m) s1v[m]=x1[(i*16+u)*3+m];
      #pragma unroll
      for(int o=0;o<3;++o){ float g=0.f;                  // p3 (K101)
        #pragma unroll
        for(int ii=0;ii<3;++ii) g += s1v[ii]*KL[26+o*3+ii];
        acc[o] += rw0*g; }
      #pragma unroll
      for(int o=0;o<3;++o){ float g=0.f;                  // p4
        #pragma unroll
        for(int ii=0;ii<3;++ii) g += s1v[ii]*BL[5+o*3+ii];
        acc[3+o] += rw1*g; }
      #pragma unroll
      for(int o=0;o<5;++o){ float g=0.f;                  // p5
        #pragma unroll
        for(int ii=0;ii<3;++ii) g += s1v[ii]*BL[14+o*3+ii];
        acc[6+o] += rw2*g; }
    } else if (t<56){
      float s2v[5];
      #pragma unroll
      for(int m=0;m<5;++m) s2v[m]=x2[(i*8+u)*5+m];
      #pragma unroll
      for(int o=0;o<5;++o){ float g=0.f;                  // p6 (K202)
        #pragma unroll
        for(int ii=0;ii<5;++ii) g += s2v[ii]*KL[155+o*5+ii];
        acc[o] += rw0*g; }
      { float g=0.f;                                      // p7
        #pragma unroll
        for(int ii=0;ii<5;++ii) g += s2v[ii]*BL[29+ii];
        acc[5] += rw1*g; }
      #pragma unroll
      for(int o=0;o<3;++o){ float g=0.f;                  // p8
        #pragma unroll
        for(int ii=0;ii<5;++ii) g += s2v[ii]*BL[34+o*5+ii];
        acc[6+o] += rw2*g; }
      #pragma unroll
      for(int o=0;o<5;++o){ float g=0.f;                  // p9
        #pragma unroll
        for(int ii=0;ii<5;++ii) g += s2v[ii]*BL[49+o*5+ii];
        acc[9+o] += rw3*g; }
    }
  }

  __syncthreads();
  // scatter accumulators: a0 | a1(u*3+m) | a2(u*5+m); concat orders: m0=[p1,p7], m1=[p3,p4,p8], m2=[p2,p5,p6,p9]
  if (t<32){
    aL[t] = acc[0];
    #pragma unroll
    for(int o=0;o<5;++o) aL[160 + t*5+o] = acc[1+o];
  } else if (t<48){
    const int uu=t-32;
    #pragma unroll
    for(int m=0;m<3;++m){ aL[40 + uu*3+m] = acc[m]; aL[40 + (16+uu)*3+m] = acc[3+m]; }
    #pragma unroll
    for(int o=0;o<5;++o) aL[160 + (32+uu)*5+o] = acc[6+o];
  } else if (t<56){
    const int uu=t-48;
    aL[32+uu] = acc[5];
    #pragma unroll
    for(int m=0;m<3;++m) aL[40 + (32+uu)*3+m] = acc[6+m];
    #pragma unroll
    for(int o=0;o<5;++o){ aL[160 + (48+uu)*5+o] = acc[o]; aL[160 + (56+uu)*5+o] = acc[9+o]; }
  }
  __syncthreads();

  const float inv40 = 0.15811388300841896660f;
  for(int q=t;q<120;q+=64){
    if (q<32){
      float g=0.f;
      for(int uu=0;uu<40;++uu) g += aL[uu]*W0[uu*32+q];
      y0[n*32+q] = g*inv40;
    } else if (q<80){
      const int e=q-32, v=e/3, m=e%3;
      float g=0.f;
      for(int uu=0;uu<40;++uu) g += aL[40+uu*3+m]*W1[uu*16+v];
      y1[n*48+e] = g*inv40;
    } else {
      const int e=q-80, tt=e/5, m=e%5;
      float g=0.f;
      for(int uu=0;uu<64;++uu) g += aL[160+uu*5+m]*W2[uu*8+tt];
      y2[n*40+e] = g*0.125f;
    }
  }
}

// =================== per-channel global stats ===================
__global__ __launch_bounds__(256) void k_stats(const float* __restrict__ y0,
                                               const float* __restrict__ y1,
                                               const float* __restrict__ y2,
                                               float* __restrict__ stats){
  const int b = blockIdx.x, t = threadIdx.x;
  __shared__ float r1[256], r2[256];
  float a1=0.f, a2=0.f;
  if (b<32){
    for(int nn=t;nn<NN;nn+=256){ float v=y0[nn*32+b]; a1+=v; a2+=v*v; }
  } else if (b<48){
    const int v_=b-32;
    for(int nn=t;nn<NN;nn+=256){
      #pragma unroll
      for(int m=0;m<3;++m){ float v=y1[nn*48+v_*3+m]; a2+=v*v; }
    }
  } else {
    const int t_=b-48;
    for(int nn=t;nn<NN;nn+=256){
      #pragma unroll
      for(int m=0;m<5;++m){ float v=y2[nn*40+t_*5+m]; a2+=v*v; }
    }
  }
  r1[t]=a1; r2[t]=a2; __syncthreads();
  for(int s=128;s>0;s>>=1){ if(t<s){ r1[t]+=r1[t+s]; r2[t]+=r2[t+s]; } __syncthreads(); }
  if(t==0){
    if(b<32){ stats[b]=r1[0]; stats[32+b]=r2[0]; }
    else if(b<48) stats[64+(b-32)]=r2[0];
    else stats[80+(b-48)]=r2[0];
  }
}

// =================== normalize + relu + residual ===================
__global__ void k_norm(const float* __restrict__ y0,const float* __restrict__ y1,const float* __restrict__ y2,
                       const float* __restrict__ stats,
                       const float* __restrict__ bw0,const float* __restrict__ bb0,
                       const float* __restrict__ bw1,const float* __restrict__ bw2,
                       float* __restrict__ x0, float* __restrict__ x1, float* __restrict__ x2){
  const int idx = blockIdx.x*256 + threadIdx.x;
  if (idx >= NN*120) return;
  const int n = idx/120, q = idx%120;
  if (q<32){
    const float mean = stats[q]*(1.f/8192.f);
    const float var  = stats[32+q]*(1.f/8192.f) - mean*mean;
    const float v = (y0[n*32+q]-mean)/sqrtf(var+1e-5f)*bw0[q]+bb0[q];
    x0[n*32+q] += fmaxf(v,0.f);
  } else if (q<80){
    const int e=q-32, v_=e/3;
    const float v = y1[n*48+e]/sqrtf(stats[64+v_]*(1.f/(8192.f*3.f))+1e-5f)*bw1[v_];
    x1[n*48+e] += fmaxf(v,0.f);
  } else {
    const int e=q-80, t_=e/5;
    const float v = y2[n*40+e]/sqrtf(stats[80+t_]*(1.f/(8192.f*5.f))+1e-5f)*bw2[t_];
    x2[n*40+e] += fmaxf(v,0.f);
  }
}

// =================== final MLP ===================
__global__ __launch_bounds__(256) void k_mlp(const float* __restrict__ x0,
                                             const float* __restrict__ Wf1,const float* __restrict__ Wf2,
                                             const float* __restrict__ bf2,const float* __restrict__ Wf3,
                                             const float* __restrict__ bf3, float* __restrict__ out){
  __shared__ float w1[1024], w2[512], w3[32], b2[16], b3[2];
  const int t=threadIdx.x;
  for(int q=t;q<1024;q+=256) w1[q]=Wf1[q];
  for(int q=t;q<512;q+=256)  w2[q]=Wf2[q];
  if(t<32) w3[t]=Wf3[t];
  if(t<16) b2[t]=bf2[t];
  if(t<2)  b3[t]=bf3[t];
  __syncthreads();
  const int n = blockIdx.x*256+t;
  if(n>=NN) return;
  float xv[32];
  #pragma unroll
  for(int k=0;k<32;++k) xv[k]=x0[n*32+k];
  const float inv32 = 0.17677669529663688110f;
  float h1[32];
  #pragma unroll 4
  for(int c=0;c<32;++c){ float g=0.f;
    #pragma unroll
    for(int k=0;k<32;++k) g+=xv[k]*w1[k*32+c];
    h1[c]=fmaxf(g*inv32,0.f); }
  float h2[16];
  #pragma unroll 4
  for(int c=0;c<16;++c){ float g=b2[c];
    #pragma unroll
    for(int k=0;k<32;++k) g+=h1[k]*w2[k*16+c];
    h2[c]=fmaxf(g,0.f); }
  #pragma unroll
  for(int m=0;m<2;++m){ float g=b3[m];
    #pragma unroll
    for(int k=0;k<16;++k) g+=h2[k]*w3[k*2+m];
    out[n*2+m]=g; }
}

extern "C" void kernel_launch(void* const* d_in, const int* in_sizes, int n_in,
                              void* d_out, int out_size, void* d_ws, size_t ws_size,
                              hipStream_t stream) {
  const float* positions = (const float*)d_in[0];
  const float* W_emb  = (const float*)d_in[1];
  const float* tp_w   = (const float*)d_in[2];
  const float* lin_W0 = (const float*)d_in[3];
  const float* lin_W1 = (const float*)d_in[4];
  const float* lin_W2 = (const float*)d_in[5];
  const float* bn_w0  = (const float*)d_in[6];
  const float* bn_b0  = (const float*)d_in[7];
  const float* bn_w1  = (const float*)d_in[8];
  const float* bn_w2  = (const float*)d_in[9];
  const float* Wf1 = (const float*)d_in[10];
  const float* Wf2 = (const float*)d_in[11];
  const float* bf2 = (const float*)d_in[12];
  const float* Wf3 = (const float*)d_in[13];
  const float* bf3 = (const float*)d_in[14];

  if (ws_size < WS_FLOATS*sizeof(float)) return;

  float* ws    = (float*)d_ws;
  float* Kbuf  = ws + OFF_K;
  float* stats = ws + OFF_STATS;
  int*   cnt   = (int*)(ws + OFF_CNT);
  int*   rev   = (int*)(ws + OFF_REV);
  float* x0 = ws + OFF_X0;
  float* x1 = ws + OFF_X1;
  float* x2 = ws + OFF_X2;
  float* y0 = ws + OFF_Y0;
  float* y1 = ws + OFF_Y1;
  float* y2 = ws + OFF_Y2;

  hipMemsetAsync(cnt, 0, NN*sizeof(int), stream);
  hipMemsetAsync(x1, 0, (size_t)(NN*48 + NN*40)*sizeof(float), stream); // x1,x2 contiguous

  k_initK<<<2,256,0,stream>>>(Kbuf);
  k_initx0<<<NN*32/256,256,0,stream>>>(W_emb, x0);
  k_knn<<<NN,256,0,stream>>>(positions, cnt, rev);

  for(int l=0;l<3;++l){
    k_msg<<<NN,64,0,stream>>>(positions, cnt, rev, Kbuf, x0, x1, x2,
                              tp_w + l*144, lin_W0 + l*40*32, lin_W1 + l*40*16, lin_W2 + l*64*8,
                              y0, y1, y2);
    k_stats<<<56,256,0,stream>>>(y0,y1,y2,stats);
    k_norm<<<(NN*120+255)/256,256,0,stream>>>(y0,y1,y2,stats,
                              bn_w0 + l*32, bn_b0 + l*32, bn_w1 + l*16, bn_w2 + l*8,
                              x0,x1,x2);
  }
  k_mlp<<<NN/256,256,0,stream>>>(x0,Wf1,Wf2,bf2,Wf3,bf3,(float*)d_out);
}

// Round 2
// 609.879 us; speedup vs baseline: 1.2903x; 1.2903x over previous
//
#include <hip/hip_runtime.h>
#include <math.h>

#define NN 8192
#define REV_CAP 64

// ---- ws layout (float element offsets) ----
static const size_t OFF_K     = 0;        // 405 floats (pad 512)
static const size_t OFF_STATS = 512;      // 96 floats (pad 640)
static const size_t OFF_CNT   = 640;      // int[8192]
static const size_t OFF_REV   = 8832;     // int[8192*64]
static const size_t OFF_X0    = 533120;   // 8192*32
static const size_t OFF_X1    = 795264;   // 8192*48
static const size_t OFF_X2    = 1188480;  // 8192*40
static const size_t OFF_Y0    = 1516160;  // 8192*32  (also aliased as SoA xs/ys/zs during KNN)
static const size_t OFF_Y1    = 1778304;  // 8192*48
static const size_t OFF_Y2    = 2171520;  // 8192*40
static const size_t WS_FLOATS = 2499200;

// =================== K tensor init (device, double precision) ===================
__device__ double dfact(int n){ double r=1.0; for(int i=2;i<=n;++i) r*=(double)i; return r; }

__device__ double dcg(int j1,int m1,int j2,int m2,int j3,int m3){
  if (m1+m2!=m3) return 0.0;
  if (j3 < abs(j1-j2) || j3 > j1+j2) return 0.0;
  double pre = sqrt((double)(2*j3+1)*dfact(j3+j1-j2)*dfact(j3-j1+j2)*dfact(j1+j2-j3)/dfact(j1+j2+j3+1));
  pre *= sqrt(dfact(j3+m3)*dfact(j3-m3)*dfact(j1-m1)*dfact(j1+m1)*dfact(j2-m2)*dfact(j2+m2));
  double s=0.0;
  for(int k=0;k<=j1+j2-j3;++k){
    int d1=j1+j2-j3-k, d2=j1-m1-k, d3=j2+m2-k, d4=j3-j2+m1+k, d5=j3-j1-m2+k;
    if(d1<0||d2<0||d3<0||d4<0||d5<0) continue;
    double den = dfact(k)*dfact(d1)*dfact(d2)*dfact(d3)*dfact(d4)*dfact(d5);
    s += ((k&1)? -1.0: 1.0)/den;
  }
  return pre*s;
}

// Q(l)[r][c], complex, per reference _Q
__device__ void qentry(int l,int r,int c,double* re,double* im){
  const double s = 0.70710678118654752440;
  *re=0.0; *im=0.0;
  if (r==l){ if(c==l) *re=1.0; return; }
  if (r>l){ int m=r-l;
    if (c==l+m) *re = ((m&1)? -s : s);
    else if (c==l-m) *re = s;
  } else { int m=l-r;
    if (c==l+m) *im = ((m&1)? s : -s);   // -i*(-1)^m*s
    else if (c==l-m) *im = s;            // i*s
  }
}

__global__ void k_initK(float* __restrict__ Kbuf){
  int tid = blockIdx.x*blockDim.x + threadIdx.x;
  if (tid >= 405) return;
  const int sizes[9]={1,25,9,45,75,25,25,75,125};
  const int l1s[9]={0,0,1,1,1,2,2,2,2};
  const int l2s[9]={0,2,0,2,2,0,2,2,2};
  const int l3s[9]={0,2,1,1,2,2,0,1,2};
  int p=0, rem=tid;
  for(p=0;p<9;++p){ if(rem < sizes[p]) break; rem -= sizes[p]; }
  int l1=l1s[p], l2=l2s[p], l3=l3s[p];
  int n1=2*l1+1, n2=2*l2+1;
  int c = rem/(n1*n2); int r2 = rem%(n1*n2); int a=r2/n2; int b=r2%n2;
  double accRe=0, accIm=0;
  for(int C=0;C<2*l3+1;++C){
    double q3re,q3im; qentry(l3,c,C,&q3re,&q3im); q3im = -q3im; // conj
    if(q3re==0.0 && q3im==0.0) continue;
    for(int A=0;A<n1;++A){
      double q1re,q1im; qentry(l1,a,A,&q1re,&q1im);
      if(q1re==0.0 && q1im==0.0) continue;
      double pre_re = q3re*q1re - q3im*q1im;
      double pre_im = q3re*q1im + q3im*q1re;
      for(int B=0;B<n2;++B){
        double q2re,q2im; qentry(l2,b,B,&q2re,&q2im);
        if(q2re==0.0 && q2im==0.0) continue;
        double cgv = dcg(l1, A-l1, l2, B-l2, l3, C-l3);
        if (cgv==0.0) continue;
        accRe += (pre_re*q2re - pre_im*q2im)*cgv;
        accIm += (pre_re*q2im + pre_im*q2re)*cgv;
      }
    }
  }
  bool useImag = ((l1+l2+l3)&1)!=0;   // parity rule == reference's max|Im|>max|Re| test
  Kbuf[tid] = (float)(useImag? accIm : accRe);
}

// =================== x0 init ===================
__global__ void k_initx0(const float* __restrict__ W_emb, float* __restrict__ x0){
  int idx = blockIdx.x*256 + threadIdx.x;
  if (idx >= NN*32) return;
  x0[idx] = W_emb[idx & 31];
}

// =================== positions AoS -> SoA ===================
__global__ void k_soa(const float* __restrict__ pos, float* __restrict__ xs,
                      float* __restrict__ ys, float* __restrict__ zs){
  int j = blockIdx.x*256 + threadIdx.x;
  if (j >= NN) return;
  xs[j]=pos[3*j]; ys[j]=pos[3*j+1]; zs[j]=pos[3*j+2];
}

// =================== exact 9-NN: one wave per node, register top-9 + shuffle merge ===================
__global__ __launch_bounds__(256) void k_knn2(const float* __restrict__ xs,
                                              const float* __restrict__ ys,
                                              const float* __restrict__ zs,
                                              int* __restrict__ cnt, int* __restrict__ rev){
  const int lane = threadIdx.x & 63;
  const int node = blockIdx.x*4 + (threadIdx.x >> 6);
  const double px = (double)xs[node], py = (double)ys[node], pz = (double)zs[node];

  double d[9]; int id[9];
  #pragma unroll
  for(int k=0;k<9;++k){ d[k]=INFINITY; id[k]=0x7fffffff; }
  double worst = INFINITY; int wslot = 0;

  for(int c=0;c<32;++c){
    const int base = (c*64 + lane)*4;
    const float4 fx = *(const float4*)(xs + base);
    const float4 fy = *(const float4*)(ys + base);
    const float4 fz = *(const float4*)(zs + base);
    #pragma unroll
    for(int q=0;q<4;++q){
      const float cx = (q==0)?fx.x:(q==1)?fx.y:(q==2)?fx.z:fx.w;
      const float cy = (q==0)?fy.x:(q==1)?fy.y:(q==2)?fy.z:fy.w;
      const float cz = (q==0)?fz.x:(q==1)?fz.y:(q==2)?fz.z:fz.w;
      const double dx=(double)cx-px, dy=(double)cy-py, dz=(double)cz-pz;
      const double d2 = dx*dx + dy*dy + dz*dz;
      if (d2 < worst){
        d[wslot]=d2; id[wslot]=base+q;
        worst=d[0]; wslot=0;
        #pragma unroll
        for(int k=1;k<9;++k){ if(d[k]>worst){ worst=d[k]; wslot=k; } }
      }
    }
  }

  // 9 rounds: global argmin over the wave's 576 candidates via shuffle butterfly
  for(int r=0;r<9;++r){
    double bv=d[0]; int bi=id[0];
    #pragma unroll
    for(int k=1;k<9;++k){
      if (d[k]<bv || (d[k]==bv && id[k]<bi)){ bv=d[k]; bi=id[k]; }
    }
    double v=bv; int ix=bi;
    #pragma unroll
    for(int s=32;s>0;s>>=1){
      double ov=__shfl_xor(v,s,64); int oi=__shfl_xor(ix,s,64);
      if (ov<v || (ov==v && oi<ix)){ v=ov; ix=oi; }
    }
    if (ix != node && lane==0){
      int cpos = atomicAdd(&cnt[ix],1);
      if (cpos < REV_CAP) rev[ix*REV_CAP + cpos] = node;
    }
    #pragma unroll
    for(int k=0;k<9;++k){
      if (id[k]==ix){ d[k]=INFINITY; id[k]=0x7fffffff; }
    }
  }
}

// =================== message passing + aggregation + linear (one wave / dst node) ===================
__global__ __launch_bounds__(64) void k_msg(
  const float* __restrict__ pos,
  const int* __restrict__ cnt, const int* __restrict__ rev,
  const float* __restrict__ Kbuf,
  const float* __restrict__ x0, const float* __restrict__ x1, const float* __restrict__ x2,
  const float* __restrict__ tpw,
  const float* __restrict__ W0, const float* __restrict__ W1, const float* __restrict__ W2,
  float* __restrict__ y0, float* __restrict__ y1, float* __restrict__ y2)
{
  const int n = blockIdx.x;
  const int t = threadIdx.x;
  __shared__ float KL[405];
  __shared__ float BL[74];    // B2[5] B4[9] B5[15] B7[5] B8[15] B9[25]
  __shared__ float aL[480];   // a0[40] | a1[40*3] | a2[64*5]
  for(int q=t;q<405;q+=64) KL[q]=Kbuf[q];

  int u=0; float rw0=0.f,rw1=0.f,rw2=0.f,rw3=0.f;
  if(t<32){ u=t; rw0=tpw[u]; rw1=tpw[32+u]; }
  else if(t<48){ u=t-32; rw0=tpw[64+u]; rw1=tpw[80+u]; rw2=tpw[96+u]; }
  else if(t<56){ u=t-48; rw0=tpw[112+u]; rw1=tpw[120+u]; rw2=tpw[128+u]; rw3=tpw[136+u]; }
  __syncthreads();

  float acc[14];
  #pragma unroll
  for(int k=0;k<14;++k) acc[k]=0.f;

  const int deg0 = cnt[n];
  const int deg = (deg0 < REV_CAP)? deg0 : REV_CAP;
  const float pjx=pos[3*n], pjy=pos[3*n+1], pjz=pos[3*n+2];

  for(int e=0;e<deg;++e){
    const int i = rev[n*REV_CAP+e];
    const float ex = pjx - pos[3*i], ey = pjy - pos[3*i+1], ez = pjz - pos[3*i+2];
    const float rn = sqrtf(ex*ex+ey*ey+ez*ez) + 1e-12f;
    const float ux = ex/rn, uy = ey/rn, uz = ez/rn;
    float sh[5];
    const float s15 = 3.8729833462f, s5 = 2.2360679775f;
    sh[0]=s15*ux*uy; sh[1]=s15*uy*uz; sh[2]=0.5f*s5*(3.f*uz*uz-1.f);
    sh[3]=s15*ux*uz; sh[4]=0.5f*s15*(ux*ux-uy*uy);

    __syncthreads();  // WAR on BL from previous edge
    for(int q=t;q<74;q+=64){
      int base;
      if (q<5)       base = 1   + q*5;         // B2 <- K022
      else if (q<14) base = 35  + (q-5)*5;     // B4 <- K121
      else if (q<29) base = 80  + (q-14)*5;    // B5 <- K122
      else if (q<34) base = 180 + (q-29)*5;    // B7 <- K220
      else if (q<49) base = 205 + (q-34)*5;    // B8 <- K221
      else           base = 280 + (q-49)*5;    // B9 <- K222
      float bv=0.f;
      #pragma unroll
      for(int j=0;j<5;++j) bv += KL[base+j]*sh[j];
      BL[q]=bv;
    }
    __syncthreads();

    if (t<32){
      const float s0 = x0[i*32+u];
      acc[0] += rw0 * s0 * KL[0];                         // p1
      #pragma unroll
      for(int o=0;o<5;++o) acc[1+o] += rw1 * s0 * BL[o];  // p2
    } else if (t<48){
      float s1v[3];
      #pragma unroll
      for(int m=0;m<3;++m) s1v[m]=x1[(i*16+u)*3+m];
      #pragma unroll
      for(int o=0;o<3;++o){ float g=0.f;                  // p3 (K101)
        #pragma unroll
        for(int ii=0;ii<3;++ii) g += s1v[ii]*KL[26+o*3+ii];
        acc[o] += rw0*g; }
      #pragma unroll
      for(int o=0;o<3;++o){ float g=0.f;                  // p4
        #pragma unroll
        for(int ii=0;ii<3;++ii) g += s1v[ii]*BL[5+o*3+ii];
        acc[3+o] += rw1*g; }
      #pragma unroll
      for(int o=0;o<5;++o){ float g=0.f;                  // p5
        #pragma unroll
        for(int ii=0;ii<3;++ii) g += s1v[ii]*BL[14+o*3+ii];
        acc[6+o] += rw2*g; }
    } else if (t<56){
      float s2v[5];
      #pragma unroll
      for(int m=0;m<5;++m) s2v[m]=x2[(i*8+u)*5+m];
      #pragma unroll
      for(int o=0;o<5;++o){ float g=0.f;                  // p6 (K202)
        #pragma unroll
        for(int ii=0;ii<5;++ii) g += s2v[ii]*KL[155+o*5+ii];
        acc[o] += rw0*g; }
      { float g=0.f;                                      // p7
        #pragma unroll
        for(int ii=0;ii<5;++ii) g += s2v[ii]*BL[29+ii];
        acc[5] += rw1*g; }
      #pragma unroll
      for(int o=0;o<3;++o){ float g=0.f;                  // p8
        #pragma unroll
        for(int ii=0;ii<5;++ii) g += s2v[ii]*BL[34+o*5+ii];
        acc[6+o] += rw2*g; }
      #pragma unroll
      for(int o=0;o<5;++o){ float g=0.f;                  // p9
        #pragma unroll
        for(int ii=0;ii<5;++ii) g += s2v[ii]*BL[49+o*5+ii];
        acc[9+o] += rw3*g; }
    }
  }

  __syncthreads();
  // scatter accumulators: a0 | a1(u*3+m) | a2(u*5+m); concat orders: m0=[p1,p7], m1=[p3,p4,p8], m2=[p2,p5,p6,p9]
  if (t<32){
    aL[t] = acc[0];
    #pragma unroll
    for(int o=0;o<5;++o) aL[160 + t*5+o] = acc[1+o];
  } else if (t<48){
    const int uu=t-32;
    #pragma unroll
    for(int m=0;m<3;++m){ aL[40 + uu*3+m] = acc[m]; aL[40 + (16+uu)*3+m] = acc[3+m]; }
    #pragma unroll
    for(int o=0;o<5;++o) aL[160 + (32+uu)*5+o] = acc[6+o];
  } else if (t<56){
    const int uu=t-48;
    aL[32+uu] = acc[5];
    #pragma unroll
    for(int m=0;m<3;++m) aL[40 + (32+uu)*3+m] = acc[6+m];
    #pragma unroll
    for(int o=0;o<5;++o){ aL[160 + (48+uu)*5+o] = acc[o]; aL[160 + (56+uu)*5+o] = acc[9+o]; }
  }
  __syncthreads();

  const float inv40 = 0.15811388300841896660f;
  for(int q=t;q<120;q+=64){
    if (q<32){
      float g=0.f;
      for(int uu=0;uu<40;++uu) g += aL[uu]*W0[uu*32+q];
      y0[n*32+q] = g*inv40;
    } else if (q<80){
      const int e=q-32, v=e/3, m=e%3;
      float g=0.f;
      for(int uu=0;uu<40;++uu) g += aL[40+uu*3+m]*W1[uu*16+v];
      y1[n*48+e] = g*inv40;
    } else {
      const int e=q-80, tt=e/5, m=e%5;
      float g=0.f;
      for(int uu=0;uu<64;++uu) g += aL[160+uu*5+m]*W2[uu*8+tt];
      y2[n*40+e] = g*0.125f;
    }
  }
}

// =================== per-channel global stats ===================
__global__ __launch_bounds__(256) void k_stats(const float* __restrict__ y0,
                                               const float* __restrict__ y1,
                                               const float* __restrict__ y2,
                                               float* __restrict__ stats){
  const int b = blockIdx.x, t = threadIdx.x;
  __shared__ float r1[256], r2[256];
  float a1=0.f, a2=0.f;
  if (b<32){
    for(int nn=t;nn<NN;nn+=256){ float v=y0[nn*32+b]; a1+=v; a2+=v*v; }
  } else if (b<48){
    const int v_=b-32;
    for(int nn=t;nn<NN;nn+=256){
      #pragma unroll
      for(int m=0;m<3;++m){ float v=y1[nn*48+v_*3+m]; a2+=v*v; }
    }
  } else {
    const int t_=b-48;
    for(int nn=t;nn<NN;nn+=256){
      #pragma unroll
      for(int m=0;m<5;++m){ float v=y2[nn*40+t_*5+m]; a2+=v*v; }
    }
  }
  r1[t]=a1; r2[t]=a2; __syncthreads();
  for(int s=128;s>0;s>>=1){ if(t<s){ r1[t]+=r1[t+s]; r2[t]+=r2[t+s]; } __syncthreads(); }
  if(t==0){
    if(b<32){ stats[b]=r1[0]; stats[32+b]=r2[0]; }
    else if(b<48) stats[64+(b-32)]=r2[0];
    else stats[80+(b-48)]=r2[0];
  }
}

// =================== normalize + relu + residual ===================
__global__ void k_norm(const float* __restrict__ y0,const float* __restrict__ y1,const float* __restrict__ y2,
                       const float* __restrict__ stats,
                       const float* __restrict__ bw0,const float* __restrict__ bb0,
                       const float* __restrict__ bw1,const float* __restrict__ bw2,
                       float* __restrict__ x0, float* __restrict__ x1, float* __restrict__ x2){
  const int idx = blockIdx.x*256 + threadIdx.x;
  if (idx >= NN*120) return;
  const int n = idx/120, q = idx%120;
  if (q<32){
    const float mean = stats[q]*(1.f/8192.f);
    const float var  = stats[32+q]*(1.f/8192.f) - mean*mean;
    const float v = (y0[n*32+q]-mean)/sqrtf(var+1e-5f)*bw0[q]+bb0[q];
    x0[n*32+q] += fmaxf(v,0.f);
  } else if (q<80){
    const int e=q-32, v_=e/3;
    const float v = y1[n*48+e]/sqrtf(stats[64+v_]*(1.f/(8192.f*3.f))+1e-5f)*bw1[v_];
    x1[n*48+e] += fmaxf(v,0.f);
  } else {
    const int e=q-80, t_=e/5;
    const float v = y2[n*40+e]/sqrtf(stats[80+t_]*(1.f/(8192.f*5.f))+1e-5f)*bw2[t_];
    x2[n*40+e] += fmaxf(v,0.f);
  }
}

// =================== final MLP ===================
__global__ __launch_bounds__(256) void k_mlp(const float* __restrict__ x0,
                                             const float* __restrict__ Wf1,const float* __restrict__ Wf2,
                                             const float* __restrict__ bf2,const float* __restrict__ Wf3,
                                             const float* __restrict__ bf3, float* __restrict__ out){
  __shared__ float w1[1024], w2[512], w3[32], b2[16], b3[2];
  const int t=threadIdx.x;
  for(int q=t;q<1024;q+=256) w1[q]=Wf1[q];
  for(int q=t;q<512;q+=256)  w2[q]=Wf2[q];
  if(t<32) w3[t]=Wf3[t];
  if(t<16) b2[t]=bf2[t];
  if(t<2)  b3[t]=bf3[t];
  __syncthreads();
  const int n = blockIdx.x*256+t;
  if(n>=NN) return;
  float xv[32];
  #pragma unroll
  for(int k=0;k<32;++k) xv[k]=x0[n*32+k];
  const float inv32 = 0.17677669529663688110f;
  float h1[32];
  #pragma unroll 4
  for(int c=0;c<32;++c){ float g=0.f;
    #pragma unroll
    for(int k=0;k<32;++k) g+=xv[k]*w1[k*32+c];
    h1[c]=fmaxf(g*inv32,0.f); }
  float h2[16];
  #pragma unroll 4
  for(int c=0;c<16;++c){ float g=b2[c];
    #pragma unroll
    for(int k=0;k<32;++k) g+=h1[k]*w2[k*16+c];
    h2[c]=fmaxf(g,0.f); }
  #pragma unroll
  for(int m=0;m<2;++m){ float g=b3[m];
    #pragma unroll
    for(int k=0;k<16;++k) g+=h2[k]*w3[k*2+m];
    out[n*2+m]=g; }
}

extern "C" void kernel_launch(void* const* d_in, const int* in_sizes, int n_in,
                              void* d_out, int out_size, void* d_ws, size_t ws_size,
                              hipStream_t stream) {
  const float* positions = (const float*)d_in[0];
  const float* W_emb  = (const float*)d_in[1];
  const float* tp_w   = (const float*)d_in[2];
  const float* lin_W0 = (const float*)d_in[3];
  const float* lin_W1 = (const float*)d_in[4];
  const float* lin_W2 = (const float*)d_in[5];
  const float* bn_w0  = (const float*)d_in[6];
  const float* bn_b0  = (const float*)d_in[7];
  const float* bn_w1  = (const float*)d_in[8];
  const float* bn_w2  = (const float*)d_in[9];
  const float* Wf1 = (const float*)d_in[10];
  const float* Wf2 = (const float*)d_in[11];
  const float* bf2 = (const float*)d_in[12];
  const float* Wf3 = (const float*)d_in[13];
  const float* bf3 = (const float*)d_in[14];

  if (ws_size < WS_FLOATS*sizeof(float)) return;

  float* ws    = (float*)d_ws;
  float* Kbuf  = ws + OFF_K;
  float* stats = ws + OFF_STATS;
  int*   cnt   = (int*)(ws + OFF_CNT);
  int*   rev   = (int*)(ws + OFF_REV);
  float* x0 = ws + OFF_X0;
  float* x1 = ws + OFF_X1;
  float* x2 = ws + OFF_X2;
  float* y0 = ws + OFF_Y0;
  float* y1 = ws + OFF_Y1;
  float* y2 = ws + OFF_Y2;

  // SoA position arrays alias the y0 region (unused until first k_msg)
  float* xs = y0;
  float* ysA = y0 + NN;
  float* zs = y0 + 2*NN;

  hipMemsetAsync(cnt, 0, NN*sizeof(int), stream);
  hipMemsetAsync(x1, 0, (size_t)(NN*48 + NN*40)*sizeof(float), stream); // x1,x2 contiguous

  k_initK<<<2,256,0,stream>>>(Kbuf);
  k_initx0<<<NN*32/256,256,0,stream>>>(W_emb, x0);
  k_soa<<<NN/256,256,0,stream>>>(positions, xs, ysA, zs);
  k_knn2<<<NN/4,256,0,stream>>>(xs, ysA, zs, cnt, rev);

  for(int l=0;l<3;++l){
    k_msg<<<NN,64,0,stream>>>(positions, cnt, rev, Kbuf, x0, x1, x2,
                              tp_w + l*144, lin_W0 + l*40*32, lin_W1 + l*40*16, lin_W2 + l*64*8,
                              y0, y1, y2);
    k_stats<<<56,256,0,stream>>>(y0,y1,y2,stats);
    k_norm<<<(NN*120+255)/256,256,0,stream>>>(y0,y1,y2,stats,
                              bn_w0 + l*32, bn_b0 + l*32, bn_w1 + l*16, bn_w2 + l*8,
                              x0,x1,x2);
  }
  k_mlp<<<NN/256,256,0,stream>>>(x0,Wf1,Wf2,bf2,Wf3,bf3,(float*)d_out);
}

// Round 3
// 507.159 us; speedup vs baseline: 1.5517x; 1.2025x over previous
//
#include <hip/hip_runtime.h>
#include <math.h>

#define NN 8192
#define REV_CAP 64

// ---- ws layout (float element offsets) ----
static const size_t OFF_K     = 0;        // 405 floats (pad 512)
static const size_t OFF_STATS = 512;      // 96 floats (pad 640)
static const size_t OFF_CNT   = 640;      // int[8192]
static const size_t OFF_REV   = 8832;     // int[8192*64]
static const size_t OFF_X0    = 533120;   // 8192*32
static const size_t OFF_X1    = 795264;   // 8192*48
static const size_t OFF_X2    = 1188480;  // 8192*40  (x1,x2 contiguous: 8192*88)
static const size_t OFF_Y0    = 1516160;  // 8192*32  (aliased as SoA xs/ys/zs during KNN)
static const size_t OFF_Y1    = 1778304;  // 8192*48
static const size_t OFF_Y2    = 2171520;  // 8192*40
static const size_t WS_FLOATS = 2499200;

// =================== K tensor math (device, double precision) ===================
__device__ double dfact(int n){ double r=1.0; for(int i=2;i<=n;++i) r*=(double)i; return r; }

__device__ double dcg(int j1,int m1,int j2,int m2,int j3,int m3){
  if (m1+m2!=m3) return 0.0;
  if (j3 < abs(j1-j2) || j3 > j1+j2) return 0.0;
  double pre = sqrt((double)(2*j3+1)*dfact(j3+j1-j2)*dfact(j3-j1+j2)*dfact(j1+j2-j3)/dfact(j1+j2+j3+1));
  pre *= sqrt(dfact(j3+m3)*dfact(j3-m3)*dfact(j1-m1)*dfact(j1+m1)*dfact(j2-m2)*dfact(j2+m2));
  double s=0.0;
  for(int k=0;k<=j1+j2-j3;++k){
    int d1=j1+j2-j3-k, d2=j1-m1-k, d3=j2+m2-k, d4=j3-j2+m1+k, d5=j3-j1-m2+k;
    if(d1<0||d2<0||d3<0||d4<0||d5<0) continue;
    double den = dfact(k)*dfact(d1)*dfact(d2)*dfact(d3)*dfact(d4)*dfact(d5);
    s += ((k&1)? -1.0: 1.0)/den;
  }
  return pre*s;
}

// Nonzeros of row r of Q(l) (<=2 per row). Returns count; cols/re/im filled.
__device__ int qrow(int l,int r,int* col,double* re,double* im){
  const double s = 0.70710678118654752440;
  if (r==l){ col[0]=l; re[0]=1.0; im[0]=0.0; return 1; }
  if (r>l){ int m=r-l;
    col[0]=l+m; re[0]=((m&1)?-s:s); im[0]=0.0;
    col[1]=l-m; re[1]=s;            im[1]=0.0;
  } else { int m=l-r;
    col[0]=l+m; re[0]=0.0; im[0]=((m&1)? s : -s);  // -i*(-1)^m*s
    col[1]=l-m; re[1]=0.0; im[1]=s;                // i*s
  }
  return 2;
}

// =================== fused setup: x0 init | zero x1x2 | SoA | zero cnt | K ===================
// virtual index space: [0,262144) x0 | [ ,983040) x12 zero | [ ,991232) soa |
//                      [ ,999424) cnt | [ ,999829) K
__global__ __launch_bounds__(256) void k_setup(const float* __restrict__ pos,
        const float* __restrict__ W_emb, float* __restrict__ Kbuf,
        float* __restrict__ x0, float* __restrict__ x12,
        float* __restrict__ xs, float* __restrict__ ys, float* __restrict__ zs,
        int* __restrict__ cnt){
  int idx = blockIdx.x*256 + threadIdx.x;
  if (idx < 262144) { x0[idx] = W_emb[idx & 31]; return; }
  idx -= 262144;
  if (idx < 720896) { x12[idx] = 0.f; return; }
  idx -= 720896;
  if (idx < 8192) { xs[idx]=pos[3*idx]; ys[idx]=pos[3*idx+1]; zs[idx]=pos[3*idx+2]; return; }
  idx -= 8192;
  if (idx < 8192) { cnt[idx]=0; return; }
  idx -= 8192;
  if (idx >= 405) return;

  const int tid = idx;
  const int sizes[9]={1,25,9,45,75,25,25,75,125};
  const int l1s[9]={0,0,1,1,1,2,2,2,2};
  const int l2s[9]={0,2,0,2,2,0,2,2,2};
  const int l3s[9]={0,2,1,1,2,2,0,1,2};
  int p=0, rem=tid;
  for(p=0;p<9;++p){ if(rem < sizes[p]) break; rem -= sizes[p]; }
  const int l1=l1s[p], l2=l2s[p], l3=l3s[p];
  const int n1=2*l1+1, n2=2*l2+1;
  const int c = rem/(n1*n2); const int r2 = rem%(n1*n2); const int a=r2/n2; const int b=r2%n2;

  int c3[2],c1[2],c2[2]; double re3[2],im3[2],re1[2],im1[2],re2[2],im2[2];
  const int nc3 = qrow(l3,c,c3,re3,im3);
  const int nc1 = qrow(l1,a,c1,re1,im1);
  const int nc2 = qrow(l2,b,c2,re2,im2);

  double accRe=0, accIm=0;
  for(int i3=0;i3<nc3;++i3){
    const double q3re=re3[i3], q3im=-im3[i3];   // conj
    for(int i1=0;i1<nc1;++i1){
      const double pre_re = q3re*re1[i1] - q3im*im1[i1];
      const double pre_im = q3re*im1[i1] + q3im*re1[i1];
      for(int i2=0;i2<nc2;++i2){
        const double cgv = dcg(l1, c1[i1]-l1, l2, c2[i2]-l2, l3, c3[i3]-l3);
        if (cgv==0.0) continue;
        accRe += (pre_re*re2[i2] - pre_im*im2[i2])*cgv;
        accIm += (pre_re*im2[i2] + pre_im*re2[i2])*cgv;
      }
    }
  }
  const bool useImag = ((l1+l2+l3)&1)!=0;   // parity rule == reference's max|Im|>max|Re| test
  Kbuf[tid] = (float)(useImag? accIm : accRe);
}

// =================== exact 9-NN (fp32): one wave per node, register top-9 + shuffle merge ===================
__global__ __launch_bounds__(256) void k_knn2(const float* __restrict__ xs,
                                              const float* __restrict__ ys,
                                              const float* __restrict__ zs,
                                              int* __restrict__ cnt, int* __restrict__ rev){
  const int lane = threadIdx.x & 63;
  const int node = blockIdx.x*4 + (threadIdx.x >> 6);
  const float px = xs[node], py = ys[node], pz = zs[node];

  float d[9]; int id[9];
  #pragma unroll
  for(int k=0;k<9;++k){ d[k]=INFINITY; id[k]=0x7fffffff; }
  float worst = INFINITY; int wslot = 0;

  for(int c=0;c<32;++c){
    const int base = (c*64 + lane)*4;
    const float4 fx = *(const float4*)(xs + base);
    const float4 fy = *(const float4*)(ys + base);
    const float4 fz = *(const float4*)(zs + base);
    float dd[4];
    { const float dx=fx.x-px, dy=fy.x-py, dz=fz.x-pz; dd[0]=dx*dx+dy*dy+dz*dz; }
    { const float dx=fx.y-px, dy=fy.y-py, dz=fz.y-pz; dd[1]=dx*dx+dy*dy+dz*dz; }
    { const float dx=fx.z-px, dy=fy.z-py, dz=fz.z-pz; dd[2]=dx*dx+dy*dy+dz*dz; }
    { const float dx=fx.w-px, dy=fy.w-py, dz=fz.w-pz; dd[3]=dx*dx+dy*dy+dz*dz; }
    #pragma unroll
    for(int q=0;q<4;++q){
      if (dd[q] < worst){
        d[wslot]=dd[q]; id[wslot]=base+q;
        worst=d[0]; wslot=0;
        #pragma unroll
        for(int k=1;k<9;++k){ if(d[k]>worst){ worst=d[k]; wslot=k; } }
      }
    }
  }

  // 9 rounds: global argmin over the wave's 576 candidates via shuffle butterfly
  for(int r=0;r<9;++r){
    float bv=d[0]; int bi=id[0];
    #pragma unroll
    for(int k=1;k<9;++k){
      if (d[k]<bv || (d[k]==bv && id[k]<bi)){ bv=d[k]; bi=id[k]; }
    }
    float v=bv; int ix=bi;
    #pragma unroll
    for(int s=32;s>0;s>>=1){
      float ov=__shfl_xor(v,s,64); int oi=__shfl_xor(ix,s,64);
      if (ov<v || (ov==v && oi<ix)){ v=ov; ix=oi; }
    }
    if (ix != node && lane==0){
      int cpos = atomicAdd(&cnt[ix],1);
      if (cpos < REV_CAP) rev[ix*REV_CAP + cpos] = node;
    }
    #pragma unroll
    for(int k=0;k<9;++k){
      if (id[k]==ix){ d[k]=INFINITY; id[k]=0x7fffffff; }
    }
  }
}

// =================== message passing + aggregation + linear (one wave / dst node) ===================
__global__ __launch_bounds__(64) void k_msg(
  const float* __restrict__ pos,
  const int* __restrict__ cnt, const int* __restrict__ rev,
  const float* __restrict__ Kbuf,
  const float* __restrict__ x0, const float* __restrict__ x1, const float* __restrict__ x2,
  const float* __restrict__ tpw,
  const float* __restrict__ W0, const float* __restrict__ W1, const float* __restrict__ W2,
  float* __restrict__ y0, float* __restrict__ y1, float* __restrict__ y2)
{
  const int n = blockIdx.x;
  const int t = threadIdx.x;
  __shared__ float KL[405];
  __shared__ float BL[74];    // B2[5] B4[9] B5[15] B7[5] B8[15] B9[25]
  __shared__ float aL[480];   // a0[40] | a1[40*3] | a2[64*5]
  for(int q=t;q<405;q+=64) KL[q]=Kbuf[q];

  int u=0; float rw0=0.f,rw1=0.f,rw2=0.f,rw3=0.f;
  if(t<32){ u=t; rw0=tpw[u]; rw1=tpw[32+u]; }
  else if(t<48){ u=t-32; rw0=tpw[64+u]; rw1=tpw[80+u]; rw2=tpw[96+u]; }
  else if(t<56){ u=t-48; rw0=tpw[112+u]; rw1=tpw[120+u]; rw2=tpw[128+u]; rw3=tpw[136+u]; }
  __syncthreads();

  float acc[14];
  #pragma unroll
  for(int k=0;k<14;++k) acc[k]=0.f;

  const int deg0 = cnt[n];
  const int deg = (deg0 < REV_CAP)? deg0 : REV_CAP;
  const float pjx=pos[3*n], pjy=pos[3*n+1], pjz=pos[3*n+2];

  for(int e=0;e<deg;++e){
    const int i = rev[n*REV_CAP+e];
    const float ex = pjx - pos[3*i], ey = pjy - pos[3*i+1], ez = pjz - pos[3*i+2];
    const float rn = sqrtf(ex*ex+ey*ey+ez*ez) + 1e-12f;
    const float ux = ex/rn, uy = ey/rn, uz = ez/rn;
    float sh[5];
    const float s15 = 3.8729833462f, s5 = 2.2360679775f;
    sh[0]=s15*ux*uy; sh[1]=s15*uy*uz; sh[2]=0.5f*s5*(3.f*uz*uz-1.f);
    sh[3]=s15*ux*uz; sh[4]=0.5f*s15*(ux*ux-uy*uy);

    __syncthreads();  // WAR on BL from previous edge
    for(int q=t;q<74;q+=64){
      int base;
      if (q<5)       base = 1   + q*5;         // B2 <- K022
      else if (q<14) base = 35  + (q-5)*5;     // B4 <- K121
      else if (q<29) base = 80  + (q-14)*5;    // B5 <- K122
      else if (q<34) base = 180 + (q-29)*5;    // B7 <- K220
      else if (q<49) base = 205 + (q-34)*5;    // B8 <- K221
      else           base = 280 + (q-49)*5;    // B9 <- K222
      float bv=0.f;
      #pragma unroll
      for(int j=0;j<5;++j) bv += KL[base+j]*sh[j];
      BL[q]=bv;
    }
    __syncthreads();

    if (t<32){
      const float s0 = x0[i*32+u];
      acc[0] += rw0 * s0 * KL[0];                         // p1
      #pragma unroll
      for(int o=0;o<5;++o) acc[1+o] += rw1 * s0 * BL[o];  // p2
    } else if (t<48){
      float s1v[3];
      #pragma unroll
      for(int m=0;m<3;++m) s1v[m]=x1[(i*16+u)*3+m];
      #pragma unroll
      for(int o=0;o<3;++o){ float g=0.f;                  // p3 (K101)
        #pragma unroll
        for(int ii=0;ii<3;++ii) g += s1v[ii]*KL[26+o*3+ii];
        acc[o] += rw0*g; }
      #pragma unroll
      for(int o=0;o<3;++o){ float g=0.f;                  // p4
        #pragma unroll
        for(int ii=0;ii<3;++ii) g += s1v[ii]*BL[5+o*3+ii];
        acc[3+o] += rw1*g; }
      #pragma unroll
      for(int o=0;o<5;++o){ float g=0.f;                  // p5
        #pragma unroll
        for(int ii=0;ii<3;++ii) g += s1v[ii]*BL[14+o*3+ii];
        acc[6+o] += rw2*g; }
    } else if (t<56){
      float s2v[5];
      #pragma unroll
      for(int m=0;m<5;++m) s2v[m]=x2[(i*8+u)*5+m];
      #pragma unroll
      for(int o=0;o<5;++o){ float g=0.f;                  // p6 (K202)
        #pragma unroll
        for(int ii=0;ii<5;++ii) g += s2v[ii]*KL[155+o*5+ii];
        acc[o] += rw0*g; }
      { float g=0.f;                                      // p7
        #pragma unroll
        for(int ii=0;ii<5;++ii) g += s2v[ii]*BL[29+ii];
        acc[5] += rw1*g; }
      #pragma unroll
      for(int o=0;o<3;++o){ float g=0.f;                  // p8
        #pragma unroll
        for(int ii=0;ii<5;++ii) g += s2v[ii]*BL[34+o*5+ii];
        acc[6+o] += rw2*g; }
      #pragma unroll
      for(int o=0;o<5;++o){ float g=0.f;                  // p9
        #pragma unroll
        for(int ii=0;ii<5;++ii) g += s2v[ii]*BL[49+o*5+ii];
        acc[9+o] += rw3*g; }
    }
  }

  __syncthreads();
  // scatter accumulators: a0 | a1(u*3+m) | a2(u*5+m); concat orders: m0=[p1,p7], m1=[p3,p4,p8], m2=[p2,p5,p6,p9]
  if (t<32){
    aL[t] = acc[0];
    #pragma unroll
    for(int o=0;o<5;++o) aL[160 + t*5+o] = acc[1+o];
  } else if (t<48){
    const int uu=t-32;
    #pragma unroll
    for(int m=0;m<3;++m){ aL[40 + uu*3+m] = acc[m]; aL[40 + (16+uu)*3+m] = acc[3+m]; }
    #pragma unroll
    for(int o=0;o<5;++o) aL[160 + (32+uu)*5+o] = acc[6+o];
  } else if (t<56){
    const int uu=t-48;
    aL[32+uu] = acc[5];
    #pragma unroll
    for(int m=0;m<3;++m) aL[40 + (32+uu)*3+m] = acc[6+m];
    #pragma unroll
    for(int o=0;o<5;++o){ aL[160 + (48+uu)*5+o] = acc[o]; aL[160 + (56+uu)*5+o] = acc[9+o]; }
  }
  __syncthreads();

  const float inv40 = 0.15811388300841896660f;
  for(int q=t;q<120;q+=64){
    if (q<32){
      float g=0.f;
      for(int uu=0;uu<40;++uu) g += aL[uu]*W0[uu*32+q];
      y0[n*32+q] = g*inv40;
    } else if (q<80){
      const int e=q-32, v=e/3, m=e%3;
      float g=0.f;
      for(int uu=0;uu<40;++uu) g += aL[40+uu*3+m]*W1[uu*16+v];
      y1[n*48+e] = g*inv40;
    } else {
      const int e=q-80, tt=e/5, m=e%5;
      float g=0.f;
      for(int uu=0;uu<64;++uu) g += aL[160+uu*5+m]*W2[uu*8+tt];
      y2[n*40+e] = g*0.125f;
    }
  }
}

// =================== per-channel global stats ===================
__global__ __launch_bounds__(256) void k_stats(const float* __restrict__ y0,
                                               const float* __restrict__ y1,
                                               const float* __restrict__ y2,
                                               float* __restrict__ stats){
  const int b = blockIdx.x, t = threadIdx.x;
  __shared__ float r1[256], r2[256];
  float a1=0.f, a2=0.f;
  if (b<32){
    for(int nn=t;nn<NN;nn+=256){ float v=y0[nn*32+b]; a1+=v; a2+=v*v; }
  } else if (b<48){
    const int v_=b-32;
    for(int nn=t;nn<NN;nn+=256){
      #pragma unroll
      for(int m=0;m<3;++m){ float v=y1[nn*48+v_*3+m]; a2+=v*v; }
    }
  } else {
    const int t_=b-48;
    for(int nn=t;nn<NN;nn+=256){
      #pragma unroll
      for(int m=0;m<5;++m){ float v=y2[nn*40+t_*5+m]; a2+=v*v; }
    }
  }
  r1[t]=a1; r2[t]=a2; __syncthreads();
  for(int s=128;s>0;s>>=1){ if(t<s){ r1[t]+=r1[t+s]; r2[t]+=r2[t+s]; } __syncthreads(); }
  if(t==0){
    if(b<32){ stats[b]=r1[0]; stats[32+b]=r2[0]; }
    else if(b<48) stats[64+(b-32)]=r2[0];
    else stats[80+(b-48)]=r2[0];
  }
}

// =================== normalize + relu + residual ===================
__global__ void k_norm(const float* __restrict__ y0,const float* __restrict__ y1,const float* __restrict__ y2,
                       const float* __restrict__ stats,
                       const float* __restrict__ bw0,const float* __restrict__ bb0,
                       const float* __restrict__ bw1,const float* __restrict__ bw2,
                       float* __restrict__ x0, float* __restrict__ x1, float* __restrict__ x2){
  const int idx = blockIdx.x*256 + threadIdx.x;
  if (idx >= NN*120) return;
  const int n = idx/120, q = idx%120;
  if (q<32){
    const float mean = stats[q]*(1.f/8192.f);
    const float var  = stats[32+q]*(1.f/8192.f) - mean*mean;
    const float v = (y0[n*32+q]-mean)/sqrtf(var+1e-5f)*bw0[q]+bb0[q];
    x0[n*32+q] += fmaxf(v,0.f);
  } else if (q<80){
    const int e=q-32, v_=e/3;
    const float v = y1[n*48+e]/sqrtf(stats[64+v_]*(1.f/(8192.f*3.f))+1e-5f)*bw1[v_];
    x1[n*48+e] += fmaxf(v,0.f);
  } else {
    const int e=q-80, t_=e/5;
    const float v = y2[n*40+e]/sqrtf(stats[80+t_]*(1.f/(8192.f*5.f))+1e-5f)*bw2[t_];
    x2[n*40+e] += fmaxf(v,0.f);
  }
}

// =================== final MLP ===================
__global__ __launch_bounds__(256) void k_mlp(const float* __restrict__ x0,
                                             const float* __restrict__ Wf1,const float* __restrict__ Wf2,
                                             const float* __restrict__ bf2,const float* __restrict__ Wf3,
                                             const float* __restrict__ bf3, float* __restrict__ out){
  __shared__ float w1[1024], w2[512], w3[32], b2[16], b3[2];
  const int t=threadIdx.x;
  for(int q=t;q<1024;q+=256) w1[q]=Wf1[q];
  for(int q=t;q<512;q+=256)  w2[q]=Wf2[q];
  if(t<32) w3[t]=Wf3[t];
  if(t<16) b2[t]=bf2[t];
  if(t<2)  b3[t]=bf3[t];
  __syncthreads();
  const int n = blockIdx.x*256+t;
  if(n>=NN) return;
  float xv[32];
  #pragma unroll
  for(int k=0;k<32;++k) xv[k]=x0[n*32+k];
  const float inv32 = 0.17677669529663688110f;
  float h1[32];
  #pragma unroll 4
  for(int c=0;c<32;++c){ float g=0.f;
    #pragma unroll
    for(int k=0;k<32;++k) g+=xv[k]*w1[k*32+c];
    h1[c]=fmaxf(g*inv32,0.f); }
  float h2[16];
  #pragma unroll 4
  for(int c=0;c<16;++c){ float g=b2[c];
    #pragma unroll
    for(int k=0;k<32;++k) g+=h1[k]*w2[k*16+c];
    h2[c]=fmaxf(g,0.f); }
  #pragma unroll
  for(int m=0;m<2;++m){ float g=b3[m];
    #pragma unroll
    for(int k=0;k<16;++k) g+=h2[k]*w3[k*2+m];
    out[n*2+m]=g; }
}

extern "C" void kernel_launch(void* const* d_in, const int* in_sizes, int n_in,
                              void* d_out, int out_size, void* d_ws, size_t ws_size,
                              hipStream_t stream) {
  const float* positions = (const float*)d_in[0];
  const float* W_emb  = (const float*)d_in[1];
  const float* tp_w   = (const float*)d_in[2];
  const float* lin_W0 = (const float*)d_in[3];
  const float* lin_W1 = (const float*)d_in[4];
  const float* lin_W2 = (const float*)d_in[5];
  const float* bn_w0  = (const float*)d_in[6];
  const float* bn_b0  = (const float*)d_in[7];
  const float* bn_w1  = (const float*)d_in[8];
  const float* bn_w2  = (const float*)d_in[9];
  const float* Wf1 = (const float*)d_in[10];
  const float* Wf2 = (const float*)d_in[11];
  const float* bf2 = (const float*)d_in[12];
  const float* Wf3 = (const float*)d_in[13];
  const float* bf3 = (const float*)d_in[14];

  if (ws_size < WS_FLOATS*sizeof(float)) return;

  float* ws    = (float*)d_ws;
  float* Kbuf  = ws + OFF_K;
  float* stats = ws + OFF_STATS;
  int*   cnt   = (int*)(ws + OFF_CNT);
  int*   rev   = (int*)(ws + OFF_REV);
  float* x0 = ws + OFF_X0;
  float* x1 = ws + OFF_X1;
  float* x2 = ws + OFF_X2;
  float* y0 = ws + OFF_Y0;
  float* y1 = ws + OFF_Y1;
  float* y2 = ws + OFF_Y2;

  // SoA position arrays alias the y0 region (unused until first k_msg)
  float* xs = y0;
  float* ysA = y0 + NN;
  float* zs = y0 + 2*NN;

  // fused setup: x0 init (262144) + x1x2 zero (720896) + soa (8192) + cnt zero (8192) + K (405)
  k_setup<<<3906,256,0,stream>>>(positions, W_emb, Kbuf, x0, x1, xs, ysA, zs, cnt);
  k_knn2<<<NN/4,256,0,stream>>>(xs, ysA, zs, cnt, rev);

  for(int l=0;l<3;++l){
    k_msg<<<NN,64,0,stream>>>(positions, cnt, rev, Kbuf, x0, x1, x2,
                              tp_w + l*144, lin_W0 + l*40*32, lin_W1 + l*40*16, lin_W2 + l*64*8,
                              y0, y1, y2);
    k_stats<<<56,256,0,stream>>>(y0,y1,y2,stats);
    k_norm<<<(NN*120+255)/256,256,0,stream>>>(y0,y1,y2,stats,
                              bn_w0 + l*32, bn_b0 + l*32, bn_w1 + l*16, bn_w2 + l*8,
                              x0,x1,x2);
  }
  k_mlp<<<NN/256,256,0,stream>>>(x0,Wf1,Wf2,bf2,Wf3,bf3,(float*)d_out);
}

// Round 4
// 437.198 us; speedup vs baseline: 1.8000x; 1.1600x over previous
//
#include <hip/hip_runtime.h>
#include <math.h>

#define NN 8192
#define REV_CAP 64
#define KNN_CAP 512   // per-wave survivor cap; P(overflow) < 1e-20 (order-stat rank bound)

// ---- ws layout (float element offsets) ----
static const size_t OFF_K     = 0;        // 405 floats (pad 512)
static const size_t OFF_STATS = 512;      // 96 floats (pad 640)
static const size_t OFF_CNT   = 640;      // int[8192]
static const size_t OFF_REV   = 8832;     // int[8192*64]
static const size_t OFF_X0    = 533120;   // 8192*32
static const size_t OFF_X1    = 795264;   // 8192*48
static const size_t OFF_X2    = 1188480;  // 8192*40  (x1,x2 contiguous: 8192*88)
static const size_t OFF_Y0    = 1516160;  // 8192*32  (aliased as SoA xs/ys/zs during KNN)
static const size_t OFF_Y1    = 1778304;  // 8192*48
static const size_t OFF_Y2    = 2171520;  // 8192*40
static const size_t WS_FLOATS = 2499200;

// =================== K tensor math (device, double precision) ===================
__device__ double dfact(int n){ double r=1.0; for(int i=2;i<=n;++i) r*=(double)i; return r; }

__device__ double dcg(int j1,int m1,int j2,int m2,int j3,int m3){
  if (m1+m2!=m3) return 0.0;
  if (j3 < abs(j1-j2) || j3 > j1+j2) return 0.0;
  double pre = sqrt((double)(2*j3+1)*dfact(j3+j1-j2)*dfact(j3-j1+j2)*dfact(j1+j2-j3)/dfact(j1+j2+j3+1));
  pre *= sqrt(dfact(j3+m3)*dfact(j3-m3)*dfact(j1-m1)*dfact(j1+m1)*dfact(j2-m2)*dfact(j2+m2));
  double s=0.0;
  for(int k=0;k<=j1+j2-j3;++k){
    int d1=j1+j2-j3-k, d2=j1-m1-k, d3=j2+m2-k, d4=j3-j2+m1+k, d5=j3-j1-m2+k;
    if(d1<0||d2<0||d3<0||d4<0||d5<0) continue;
    double den = dfact(k)*dfact(d1)*dfact(d2)*dfact(d3)*dfact(d4)*dfact(d5);
    s += ((k&1)? -1.0: 1.0)/den;
  }
  return pre*s;
}

// Nonzeros of row r of Q(l) (<=2 per row). Returns count; cols/re/im filled.
__device__ int qrow(int l,int r,int* col,double* re,double* im){
  const double s = 0.70710678118654752440;
  if (r==l){ col[0]=l; re[0]=1.0; im[0]=0.0; return 1; }
  if (r>l){ int m=r-l;
    col[0]=l+m; re[0]=((m&1)?-s:s); im[0]=0.0;
    col[1]=l-m; re[1]=s;            im[1]=0.0;
  } else { int m=l-r;
    col[0]=l+m; re[0]=0.0; im[0]=((m&1)? s : -s);  // -i*(-1)^m*s
    col[1]=l-m; re[1]=0.0; im[1]=s;                // i*s
  }
  return 2;
}

// =================== fused setup: x0 init | zero x1x2 | SoA | zero cnt | K ===================
__global__ __launch_bounds__(256) void k_setup(const float* __restrict__ pos,
        const float* __restrict__ W_emb, float* __restrict__ Kbuf,
        float* __restrict__ x0, float* __restrict__ x12,
        float* __restrict__ xs, float* __restrict__ ys, float* __restrict__ zs,
        int* __restrict__ cnt){
  int idx = blockIdx.x*256 + threadIdx.x;
  if (idx < 262144) { x0[idx] = W_emb[idx & 31]; return; }
  idx -= 262144;
  if (idx < 720896) { x12[idx] = 0.f; return; }
  idx -= 720896;
  if (idx < 8192) { xs[idx]=pos[3*idx]; ys[idx]=pos[3*idx+1]; zs[idx]=pos[3*idx+2]; return; }
  idx -= 8192;
  if (idx < 8192) { cnt[idx]=0; return; }
  idx -= 8192;
  if (idx >= 405) return;

  const int tid = idx;
  const int sizes[9]={1,25,9,45,75,25,25,75,125};
  const int l1s[9]={0,0,1,1,1,2,2,2,2};
  const int l2s[9]={0,2,0,2,2,0,2,2,2};
  const int l3s[9]={0,2,1,1,2,2,0,1,2};
  int p=0, rem=tid;
  for(p=0;p<9;++p){ if(rem < sizes[p]) break; rem -= sizes[p]; }
  const int l1=l1s[p], l2=l2s[p], l3=l3s[p];
  const int n1=2*l1+1, n2=2*l2+1;
  const int c = rem/(n1*n2); const int r2 = rem%(n1*n2); const int a=r2/n2; const int b=r2%n2;

  int c3[2],c1[2],c2[2]; double re3[2],im3[2],re1[2],im1[2],re2[2],im2[2];
  const int nc3 = qrow(l3,c,c3,re3,im3);
  const int nc1 = qrow(l1,a,c1,re1,im1);
  const int nc2 = qrow(l2,b,c2,re2,im2);

  double accRe=0, accIm=0;
  for(int i3=0;i3<nc3;++i3){
    const double q3re=re3[i3], q3im=-im3[i3];   // conj
    for(int i1=0;i1<nc1;++i1){
      const double pre_re = q3re*re1[i1] - q3im*im1[i1];
      const double pre_im = q3re*im1[i1] + q3im*re1[i1];
      for(int i2=0;i2<nc2;++i2){
        const double cgv = dcg(l1, c1[i1]-l1, l2, c2[i2]-l2, l3, c3[i3]-l3);
        if (cgv==0.0) continue;
        accRe += (pre_re*re2[i2] - pre_im*im2[i2])*cgv;
        accIm += (pre_re*im2[i2] + pre_im*re2[i2])*cgv;
      }
    }
  }
  const bool useImag = ((l1+l2+l3)&1)!=0;
  Kbuf[tid] = (float)(useImag? accIm : accRe);
}

// =================== exact 9-NN (fp32): sample bound + filter + exact refine ===================
__global__ __launch_bounds__(256) void k_knn3(const float* __restrict__ xs,
                                              const float* __restrict__ ys,
                                              const float* __restrict__ zs,
                                              int* __restrict__ cnt, int* __restrict__ rev){
  const int lane = threadIdx.x & 63;
  const int w    = threadIdx.x >> 6;
  const int node = blockIdx.x*4 + w;
  __shared__ float sdist[4][KNN_CAP];
  __shared__ int   sidx[4][KNN_CAP];
  __shared__ int   scount[4];
  if (threadIdx.x < 4) scount[threadIdx.x]=0;
  __syncthreads();

  const float px = xs[node], py = ys[node], pz = zs[node];

  // ---- Phase 1: per-lane top-9 of first 1024 candidates (16/lane) ----
  float d9[9]; int id9[9];
  #pragma unroll
  for(int k=0;k<9;++k){ d9[k]=INFINITY; id9[k]=0x7fffffff; }
  float worst = INFINITY; int wslot = 0;
  for(int c=0;c<4;++c){
    const int base = (c*64 + lane)*4;
    const float4 fx = *(const float4*)(xs + base);
    const float4 fy = *(const float4*)(ys + base);
    const float4 fz = *(const float4*)(zs + base);
    float dd[4];
    { const float dx=fx.x-px, dy=fy.x-py, dz=fz.x-pz; dd[0]=dx*dx+dy*dy+dz*dz; }
    { const float dx=fx.y-px, dy=fy.y-py, dz=fz.y-pz; dd[1]=dx*dx+dy*dy+dz*dz; }
    { const float dx=fx.z-px, dy=fy.z-py, dz=fz.z-pz; dd[2]=dx*dx+dy*dy+dz*dz; }
    { const float dx=fx.w-px, dy=fy.w-py, dz=fz.w-pz; dd[3]=dx*dx+dy*dy+dz*dz; }
    #pragma unroll
    for(int q=0;q<4;++q){
      if (dd[q] < worst){
        d9[wslot]=dd[q]; id9[wslot]=base+q;
        worst=d9[0]; wslot=0;
        #pragma unroll
        for(int k=1;k<9;++k){ if(d9[k]>worst){ worst=d9[k]; wslot=k; } }
      }
    }
  }
  // merge: T = 9th smallest of the 1024-sample (>= true global 9th)
  float T = INFINITY;
  for(int r=0;r<9;++r){
    float bv=d9[0]; int bi=id9[0];
    #pragma unroll
    for(int k=1;k<9;++k){
      if (d9[k]<bv || (d9[k]==bv && id9[k]<bi)){ bv=d9[k]; bi=id9[k]; }
    }
    float v=bv; int ix=bi;
    #pragma unroll
    for(int s=32;s>0;s>>=1){
      float ov=__shfl_xor(v,s,64); int oi=__shfl_xor(ix,s,64);
      if (ov<v || (ov==v && oi<ix)){ v=ov; ix=oi; }
    }
    T = v;
    #pragma unroll
    for(int k=0;k<9;++k){
      if (id9[k]==ix){ d9[k]=INFINITY; id9[k]=0x7fffffff; }
    }
  }

  // ---- Phase 2: filter all 8192 candidates by d <= T into per-wave LDS buffer ----
  for(int c=0;c<32;++c){
    const int base = (c*64 + lane)*4;
    const float4 fx = *(const float4*)(xs + base);
    const float4 fy = *(const float4*)(ys + base);
    const float4 fz = *(const float4*)(zs + base);
    float dd[4];
    { const float dx=fx.x-px, dy=fy.x-py, dz=fz.x-pz; dd[0]=dx*dx+dy*dy+dz*dz; }
    { const float dx=fx.y-px, dy=fy.y-py, dz=fz.y-pz; dd[1]=dx*dx+dy*dy+dz*dz; }
    { const float dx=fx.z-px, dy=fy.z-py, dz=fz.z-pz; dd[2]=dx*dx+dy*dy+dz*dz; }
    { const float dx=fx.w-px, dy=fy.w-py, dz=fz.w-pz; dd[3]=dx*dx+dy*dy+dz*dz; }
    #pragma unroll
    for(int q=0;q<4;++q){
      if (dd[q] <= T){
        int pos = atomicAdd(&scount[w],1);
        if (pos < KNN_CAP){ sdist[w][pos]=dd[q]; sidx[w][pos]=base+q; }
      }
    }
  }
  __syncthreads();

  // ---- Phase 3: exact top-9 over survivors, (d,id)-lexicographic ----
  int m = scount[w]; if (m > KNN_CAP) m = KNN_CAP;
  float dl[KNN_CAP/64]; int il[KNN_CAP/64];
  #pragma unroll
  for(int k=0;k<KNN_CAP/64;++k){
    const int j = lane + 64*k;
    if (j < m){ dl[k]=sdist[w][j]; il[k]=sidx[w][j]; }
    else      { dl[k]=INFINITY;    il[k]=0x7fffffff; }
  }
  for(int r=0;r<9;++r){
    float bv=dl[0]; int bi=il[0];
    #pragma unroll
    for(int k=1;k<KNN_CAP/64;++k){
      if (dl[k]<bv || (dl[k]==bv && il[k]<bi)){ bv=dl[k]; bi=il[k]; }
    }
    float v=bv; int ix=bi;
    #pragma unroll
    for(int s=32;s>0;s>>=1){
      float ov=__shfl_xor(v,s,64); int oi=__shfl_xor(ix,s,64);
      if (ov<v || (ov==v && oi<ix)){ v=ov; ix=oi; }
    }
    if (ix != node && lane==0){
      int cpos = atomicAdd(&cnt[ix],1);
      if (cpos < REV_CAP) rev[ix*REV_CAP + cpos] = node;
    }
    #pragma unroll
    for(int k=0;k<KNN_CAP/64;++k){
      if (il[k]==ix){ dl[k]=INFINITY; il[k]=0x7fffffff; }
    }
  }
}

// =================== message passing + aggregation + linear (one wave / dst node) ===================
__global__ __launch_bounds__(64) void k_msg(
  const float* __restrict__ pos,
  const int* __restrict__ cnt, const int* __restrict__ rev,
  const float* __restrict__ Kbuf,
  const float* __restrict__ x0, const float* __restrict__ x1, const float* __restrict__ x2,
  const float* __restrict__ tpw,
  const float* __restrict__ W0, const float* __restrict__ W1, const float* __restrict__ W2,
  float* __restrict__ y0, float* __restrict__ y1, float* __restrict__ y2,
  float* __restrict__ stats)
{
  const int n = blockIdx.x;
  const int t = threadIdx.x;
  // block 0 zeroes the stats accumulator for this layer (k_stats runs after all k_msg blocks)
  if (n==0){ stats[t]=0.f; if (t<32) stats[64+t]=0.f; }
  __shared__ float KL[405];
  __shared__ float BL[74];    // B2[5] B4[9] B5[15] B7[5] B8[15] B9[25]
  __shared__ float aL[480];   // a0[40] | a1[40*3] | a2[64*5]
  for(int q=t;q<405;q+=64) KL[q]=Kbuf[q];

  int u=0; float rw0=0.f,rw1=0.f,rw2=0.f,rw3=0.f;
  if(t<32){ u=t; rw0=tpw[u]; rw1=tpw[32+u]; }
  else if(t<48){ u=t-32; rw0=tpw[64+u]; rw1=tpw[80+u]; rw2=tpw[96+u]; }
  else if(t<56){ u=t-48; rw0=tpw[112+u]; rw1=tpw[120+u]; rw2=tpw[128+u]; rw3=tpw[136+u]; }
  __syncthreads();

  float acc[14];
  #pragma unroll
  for(int k=0;k<14;++k) acc[k]=0.f;

  const int deg0 = cnt[n];
  const int deg = (deg0 < REV_CAP)? deg0 : REV_CAP;
  const float pjx=pos[3*n], pjy=pos[3*n+1], pjz=pos[3*n+2];

  for(int e=0;e<deg;++e){
    const int i = rev[n*REV_CAP+e];
    const float ex = pjx - pos[3*i], ey = pjy - pos[3*i+1], ez = pjz - pos[3*i+2];
    const float rn = sqrtf(ex*ex+ey*ey+ez*ez) + 1e-12f;
    const float ux = ex/rn, uy = ey/rn, uz = ez/rn;
    float sh[5];
    const float s15 = 3.8729833462f, s5 = 2.2360679775f;
    sh[0]=s15*ux*uy; sh[1]=s15*uy*uz; sh[2]=0.5f*s5*(3.f*uz*uz-1.f);
    sh[3]=s15*ux*uz; sh[4]=0.5f*s15*(ux*ux-uy*uy);

    __syncthreads();  // WAR on BL from previous edge
    for(int q=t;q<74;q+=64){
      int base;
      if (q<5)       base = 1   + q*5;         // B2 <- K022
      else if (q<14) base = 35  + (q-5)*5;     // B4 <- K121
      else if (q<29) base = 80  + (q-14)*5;    // B5 <- K122
      else if (q<34) base = 180 + (q-29)*5;    // B7 <- K220
      else if (q<49) base = 205 + (q-34)*5;    // B8 <- K221
      else           base = 280 + (q-49)*5;    // B9 <- K222
      float bv=0.f;
      #pragma unroll
      for(int j=0;j<5;++j) bv += KL[base+j]*sh[j];
      BL[q]=bv;
    }
    __syncthreads();

    if (t<32){
      const float s0 = x0[i*32+u];
      acc[0] += rw0 * s0 * KL[0];                         // p1
      #pragma unroll
      for(int o=0;o<5;++o) acc[1+o] += rw1 * s0 * BL[o];  // p2
    } else if (t<48){
      float s1v[3];
      #pragma unroll
      for(int m=0;m<3;++m) s1v[m]=x1[(i*16+u)*3+m];
      #pragma unroll
      for(int o=0;o<3;++o){ float g=0.f;                  // p3 (K101)
        #pragma unroll
        for(int ii=0;ii<3;++ii) g += s1v[ii]*KL[26+o*3+ii];
        acc[o] += rw0*g; }
      #pragma unroll
      for(int o=0;o<3;++o){ float g=0.f;                  // p4
        #pragma unroll
        for(int ii=0;ii<3;++ii) g += s1v[ii]*BL[5+o*3+ii];
        acc[3+o] += rw1*g; }
      #pragma unroll
      for(int o=0;o<5;++o){ float g=0.f;                  // p5
        #pragma unroll
        for(int ii=0;ii<3;++ii) g += s1v[ii]*BL[14+o*3+ii];
        acc[6+o] += rw2*g; }
    } else if (t<56){
      float s2v[5];
      #pragma unroll
      for(int m=0;m<5;++m) s2v[m]=x2[(i*8+u)*5+m];
      #pragma unroll
      for(int o=0;o<5;++o){ float g=0.f;                  // p6 (K202)
        #pragma unroll
        for(int ii=0;ii<5;++ii) g += s2v[ii]*KL[155+o*5+ii];
        acc[o] += rw0*g; }
      { float g=0.f;                                      // p7
        #pragma unroll
        for(int ii=0;ii<5;++ii) g += s2v[ii]*BL[29+ii];
        acc[5] += rw1*g; }
      #pragma unroll
      for(int o=0;o<3;++o){ float g=0.f;                  // p8
        #pragma unroll
        for(int ii=0;ii<5;++ii) g += s2v[ii]*BL[34+o*5+ii];
        acc[6+o] += rw2*g; }
      #pragma unroll
      for(int o=0;o<5;++o){ float g=0.f;                  // p9
        #pragma unroll
        for(int ii=0;ii<5;++ii) g += s2v[ii]*BL[49+o*5+ii];
        acc[9+o] += rw3*g; }
    }
  }

  __syncthreads();
  if (t<32){
    aL[t] = acc[0];
    #pragma unroll
    for(int o=0;o<5;++o) aL[160 + t*5+o] = acc[1+o];
  } else if (t<48){
    const int uu=t-32;
    #pragma unroll
    for(int m=0;m<3;++m){ aL[40 + uu*3+m] = acc[m]; aL[40 + (16+uu)*3+m] = acc[3+m]; }
    #pragma unroll
    for(int o=0;o<5;++o) aL[160 + (32+uu)*5+o] = acc[6+o];
  } else if (t<56){
    const int uu=t-48;
    aL[32+uu] = acc[5];
    #pragma unroll
    for(int m=0;m<3;++m) aL[40 + (32+uu)*3+m] = acc[6+m];
    #pragma unroll
    for(int o=0;o<5;++o){ aL[160 + (48+uu)*5+o] = acc[o]; aL[160 + (56+uu)*5+o] = acc[9+o]; }
  }
  __syncthreads();

  const float inv40 = 0.15811388300841896660f;
  for(int q=t;q<120;q+=64){
    if (q<32){
      float g=0.f;
      for(int uu=0;uu<40;++uu) g += aL[uu]*W0[uu*32+q];
      y0[n*32+q] = g*inv40;
    } else if (q<80){
      const int e=q-32, v=e/3, m=e%3;
      float g=0.f;
      for(int uu=0;uu<40;++uu) g += aL[40+uu*3+m]*W1[uu*16+v];
      y1[n*48+e] = g*inv40;
    } else {
      const int e=q-80, tt=e/5, m=e%5;
      float g=0.f;
      for(int uu=0;uu<64;++uu) g += aL[160+uu*5+m]*W2[uu*8+tt];
      y2[n*40+e] = g*0.125f;
    }
  }
}

// =================== per-channel global stats: 96 ch x 8 chunks, atomic accumulate ===================
__global__ __launch_bounds__(256) void k_stats(const float* __restrict__ y0,
                                               const float* __restrict__ y1,
                                               const float* __restrict__ y2,
                                               float* __restrict__ stats){
  const int ch = blockIdx.x % 96;
  const int chunk = blockIdx.x / 96;
  const int t = threadIdx.x;
  const int n0 = chunk*1024;
  __shared__ float r1[256], r2[256];
  float a1=0.f, a2=0.f;
  if (ch<32){
    for(int nn=t;nn<1024;nn+=256){ float v=y0[(n0+nn)*32+ch]; a1+=v; a2+=v*v; }
  } else if (ch<48){
    const int v_=ch-32;
    for(int nn=t;nn<1024;nn+=256){
      #pragma unroll
      for(int m=0;m<3;++m){ float v=y1[(n0+nn)*48+v_*3+m]; a2+=v*v; }
    }
  } else {
    const int t_=ch-48;
    for(int nn=t;nn<1024;nn+=256){
      #pragma unroll
      for(int m=0;m<5;++m){ float v=y2[(n0+nn)*40+t_*5+m]; a2+=v*v; }
    }
  }
  r1[t]=a1; r2[t]=a2; __syncthreads();
  for(int s=128;s>0;s>>=1){ if(t<s){ r1[t]+=r1[t+s]; r2[t]+=r2[t+s]; } __syncthreads(); }
  if(t==0){
    if(ch<32){ atomicAdd(&stats[ch], r1[0]); atomicAdd(&stats[32+ch], r2[0]); }
    else if(ch<48) atomicAdd(&stats[64+(ch-32)], r2[0]);
    else atomicAdd(&stats[80+(ch-48)], r2[0]);
  }
}

// =================== normalize + relu + residual ===================
__global__ void k_norm(const float* __restrict__ y0,const float* __restrict__ y1,const float* __restrict__ y2,
                       const float* __restrict__ stats,
                       const float* __restrict__ bw0,const float* __restrict__ bb0,
                       const float* __restrict__ bw1,const float* __restrict__ bw2,
                       float* __restrict__ x0, float* __restrict__ x1, float* __restrict__ x2){
  const int idx = blockIdx.x*256 + threadIdx.x;
  if (idx >= NN*120) return;
  const int n = idx/120, q = idx%120;
  if (q<32){
    const float mean = stats[q]*(1.f/8192.f);
    const float var  = stats[32+q]*(1.f/8192.f) - mean*mean;
    const float v = (y0[n*32+q]-mean)/sqrtf(var+1e-5f)*bw0[q]+bb0[q];
    x0[n*32+q] += fmaxf(v,0.f);
  } else if (q<80){
    const int e=q-32, v_=e/3;
    const float v = y1[n*48+e]/sqrtf(stats[64+v_]*(1.f/(8192.f*3.f))+1e-5f)*bw1[v_];
    x1[n*48+e] += fmaxf(v,0.f);
  } else {
    const int e=q-80, t_=e/5;
    const float v = y2[n*40+e]/sqrtf(stats[80+t_]*(1.f/(8192.f*5.f))+1e-5f)*bw2[t_];
    x2[n*40+e] += fmaxf(v,0.f);
  }
}

// =================== final MLP ===================
__global__ __launch_bounds__(256) void k_mlp(const float* __restrict__ x0,
                                             const float* __restrict__ Wf1,const float* __restrict__ Wf2,
                                             const float* __restrict__ bf2,const float* __restrict__ Wf3,
                                             const float* __restrict__ bf3, float* __restrict__ out){
  __shared__ float w1[1024], w2[512], w3[32], b2[16], b3[2];
  const int t=threadIdx.x;
  for(int q=t;q<1024;q+=256) w1[q]=Wf1[q];
  for(int q=t;q<512;q+=256)  w2[q]=Wf2[q];
  if(t<32) w3[t]=Wf3[t];
  if(t<16) b2[t]=bf2[t];
  if(t<2)  b3[t]=bf3[t];
  __syncthreads();
  const int n = blockIdx.x*256+t;
  if(n>=NN) return;
  float xv[32];
  #pragma unroll
  for(int k=0;k<32;++k) xv[k]=x0[n*32+k];
  const float inv32 = 0.17677669529663688110f;
  float h1[32];
  #pragma unroll 4
  for(int c=0;c<32;++c){ float g=0.f;
    #pragma unroll
    for(int k=0;k<32;++k) g+=xv[k]*w1[k*32+c];
    h1[c]=fmaxf(g*inv32,0.f); }
  float h2[16];
  #pragma unroll 4
  for(int c=0;c<16;++c){ float g=b2[c];
    #pragma unroll
    for(int k=0;k<32;++k) g+=h1[k]*w2[k*16+c];
    h2[c]=fmaxf(g,0.f); }
  #pragma unroll
  for(int m=0;m<2;++m){ float g=b3[m];
    #pragma unroll
    for(int k=0;k<16;++k) g+=h2[k]*w3[k*2+m];
    out[n*2+m]=g; }
}

extern "C" void kernel_launch(void* const* d_in, const int* in_sizes, int n_in,
                              void* d_out, int out_size, void* d_ws, size_t ws_size,
                              hipStream_t stream) {
  const float* positions = (const float*)d_in[0];
  const float* W_emb  = (const float*)d_in[1];
  const float* tp_w   = (const float*)d_in[2];
  const float* lin_W0 = (const float*)d_in[3];
  const float* lin_W1 = (const float*)d_in[4];
  const float* lin_W2 = (const float*)d_in[5];
  const float* bn_w0  = (const float*)d_in[6];
  const float* bn_b0  = (const float*)d_in[7];
  const float* bn_w1  = (const float*)d_in[8];
  const float* bn_w2  = (const float*)d_in[9];
  const float* Wf1 = (const float*)d_in[10];
  const float* Wf2 = (const float*)d_in[11];
  const float* bf2 = (const float*)d_in[12];
  const float* Wf3 = (const float*)d_in[13];
  const float* bf3 = (const float*)d_in[14];

  if (ws_size < WS_FLOATS*sizeof(float)) return;

  float* ws    = (float*)d_ws;
  float* Kbuf  = ws + OFF_K;
  float* stats = ws + OFF_STATS;
  int*   cnt   = (int*)(ws + OFF_CNT);
  int*   rev   = (int*)(ws + OFF_REV);
  float* x0 = ws + OFF_X0;
  float* x1 = ws + OFF_X1;
  float* x2 = ws + OFF_X2;
  float* y0 = ws + OFF_Y0;
  float* y1 = ws + OFF_Y1;
  float* y2 = ws + OFF_Y2;

  // SoA position arrays alias the y0 region (unused until first k_msg)
  float* xs = y0;
  float* ysA = y0 + NN;
  float* zs = y0 + 2*NN;

  k_setup<<<3906,256,0,stream>>>(positions, W_emb, Kbuf, x0, x1, xs, ysA, zs, cnt);
  k_knn3<<<NN/4,256,0,stream>>>(xs, ysA, zs, cnt, rev);

  for(int l=0;l<3;++l){
    k_msg<<<NN,64,0,stream>>>(positions, cnt, rev, Kbuf, x0, x1, x2,
                              tp_w + l*144, lin_W0 + l*40*32, lin_W1 + l*40*16, lin_W2 + l*64*8,
                              y0, y1, y2, stats);
    k_stats<<<768,256,0,stream>>>(y0,y1,y2,stats);
    k_norm<<<(NN*120+255)/256,256,0,stream>>>(y0,y1,y2,stats,
                              bn_w0 + l*32, bn_b0 + l*32, bn_w1 + l*16, bn_w2 + l*8,
                              x0,x1,x2);
  }
  k_mlp<<<NN/256,256,0,stream>>>(x0,Wf1,Wf2,bf2,Wf3,bf3,(float*)d_out);
}

// Round 5
// 345.694 us; speedup vs baseline: 2.2764x; 1.2647x over previous
//
#include <hip/hip_runtime.h>
#include <math.h>

#define NN 8192
#define REV_CAP 64
#define KNN_CAP 512   // per-wave survivor cap; P(overflow) < 1e-20 (order-stat rank bound)

// ---- ws layout (float element offsets) ----
static const size_t OFF_K     = 0;        // 405 floats (pad 512)
static const size_t OFF_STATS = 512;      // 96 floats (pad 640)
static const size_t OFF_CNT   = 640;      // int[8192]
static const size_t OFF_REV   = 8832;     // int[8192*64]
static const size_t OFF_XF    = 533120;   // 8192*120 interleaved features (l0|l1|l2)
static const size_t OFF_YF    = 1516160;  // 8192*120 layer outputs (head aliased as SoA xs/ys/zs for KNN)
static const size_t WS_FLOATS = 2499200;

// =================== K tensor math (device, double precision) ===================
__device__ double dfact(int n){ double r=1.0; for(int i=2;i<=n;++i) r*=(double)i; return r; }

__device__ double dcg(int j1,int m1,int j2,int m2,int j3,int m3){
  if (m1+m2!=m3) return 0.0;
  if (j3 < abs(j1-j2) || j3 > j1+j2) return 0.0;
  double pre = sqrt((double)(2*j3+1)*dfact(j3+j1-j2)*dfact(j3-j1+j2)*dfact(j1+j2-j3)/dfact(j1+j2+j3+1));
  pre *= sqrt(dfact(j3+m3)*dfact(j3-m3)*dfact(j1-m1)*dfact(j1+m1)*dfact(j2-m2)*dfact(j2+m2));
  double s=0.0;
  for(int k=0;k<=j1+j2-j3;++k){
    int d1=j1+j2-j3-k, d2=j1-m1-k, d3=j2+m2-k, d4=j3-j2+m1+k, d5=j3-j1-m2+k;
    if(d1<0||d2<0||d3<0||d4<0||d5<0) continue;
    double den = dfact(k)*dfact(d1)*dfact(d2)*dfact(d3)*dfact(d4)*dfact(d5);
    s += ((k&1)? -1.0: 1.0)/den;
  }
  return pre*s;
}

// Nonzeros of row r of Q(l) (<=2 per row).
__device__ int qrow(int l,int r,int* col,double* re,double* im){
  const double s = 0.70710678118654752440;
  if (r==l){ col[0]=l; re[0]=1.0; im[0]=0.0; return 1; }
  if (r>l){ int m=r-l;
    col[0]=l+m; re[0]=((m&1)?-s:s); im[0]=0.0;
    col[1]=l-m; re[1]=s;            im[1]=0.0;
  } else { int m=l-r;
    col[0]=l+m; re[0]=0.0; im[0]=((m&1)? s : -s);  // -i*(-1)^m*s
    col[1]=l-m; re[1]=0.0; im[1]=s;                // i*s
  }
  return 2;
}

// =================== fused setup: xf init | SoA | zero cnt | K ===================
// virtual idx: [0,983040) xf | [ ,+8192) soa | [ ,+8192) cnt | [ ,+405) K
__global__ __launch_bounds__(256) void k_setup(const float* __restrict__ pos,
        const float* __restrict__ W_emb, float* __restrict__ Kbuf,
        float* __restrict__ xf,
        float* __restrict__ xs, float* __restrict__ ys, float* __restrict__ zs,
        int* __restrict__ cnt){
  int idx = blockIdx.x*256 + threadIdx.x;
  if (idx < 983040) { const int c = idx%120; xf[idx] = (c<32)? W_emb[c] : 0.f; return; }
  idx -= 983040;
  if (idx < 8192) { xs[idx]=pos[3*idx]; ys[idx]=pos[3*idx+1]; zs[idx]=pos[3*idx+2]; return; }
  idx -= 8192;
  if (idx < 8192) { cnt[idx]=0; return; }
  idx -= 8192;
  if (idx >= 405) return;

  const int tid = idx;
  const int sizes[9]={1,25,9,45,75,25,25,75,125};
  const int l1s[9]={0,0,1,1,1,2,2,2,2};
  const int l2s[9]={0,2,0,2,2,0,2,2,2};
  const int l3s[9]={0,2,1,1,2,2,0,1,2};
  int p=0, rem=tid;
  for(p=0;p<9;++p){ if(rem < sizes[p]) break; rem -= sizes[p]; }
  const int l1=l1s[p], l2=l2s[p], l3=l3s[p];
  const int n1=2*l1+1, n2=2*l2+1;
  const int c = rem/(n1*n2); const int r2 = rem%(n1*n2); const int a=r2/n2; const int b=r2%n2;

  int c3[2],c1[2],c2[2]; double re3[2],im3[2],re1[2],im1[2],re2[2],im2[2];
  const int nc3 = qrow(l3,c,c3,re3,im3);
  const int nc1 = qrow(l1,a,c1,re1,im1);
  const int nc2 = qrow(l2,b,c2,re2,im2);

  double accRe=0, accIm=0;
  for(int i3=0;i3<nc3;++i3){
    const double q3re=re3[i3], q3im=-im3[i3];   // conj
    for(int i1=0;i1<nc1;++i1){
      const double pre_re = q3re*re1[i1] - q3im*im1[i1];
      const double pre_im = q3re*im1[i1] + q3im*re1[i1];
      for(int i2=0;i2<nc2;++i2){
        const double cgv = dcg(l1, c1[i1]-l1, l2, c2[i2]-l2, l3, c3[i3]-l3);
        if (cgv==0.0) continue;
        accRe += (pre_re*re2[i2] - pre_im*im2[i2])*cgv;
        accIm += (pre_re*im2[i2] + pre_im*re2[i2])*cgv;
      }
    }
  }
  const bool useImag = ((l1+l2+l3)&1)!=0;
  Kbuf[tid] = (float)(useImag? accIm : accRe);
}

// =================== exact 9-NN (fp32): sample bound + filter + exact refine ===================
__global__ __launch_bounds__(256) void k_knn3(const float* __restrict__ xs,
                                              const float* __restrict__ ys,
                                              const float* __restrict__ zs,
                                              int* __restrict__ cnt, int* __restrict__ rev){
  const int lane = threadIdx.x & 63;
  const int w    = threadIdx.x >> 6;
  const int node = blockIdx.x*4 + w;
  __shared__ float sdist[4][KNN_CAP];
  __shared__ int   sidx[4][KNN_CAP];
  __shared__ int   scount[4];
  if (threadIdx.x < 4) scount[threadIdx.x]=0;
  __syncthreads();

  const float px = xs[node], py = ys[node], pz = zs[node];

  // Phase 1: top-9 of first 1024 candidates
  float d9[9]; int id9[9];
  #pragma unroll
  for(int k=0;k<9;++k){ d9[k]=INFINITY; id9[k]=0x7fffffff; }
  float worst = INFINITY; int wslot = 0;
  for(int c=0;c<4;++c){
    const int base = (c*64 + lane)*4;
    const float4 fx = *(const float4*)(xs + base);
    const float4 fy = *(const float4*)(ys + base);
    const float4 fz = *(const float4*)(zs + base);
    float dd[4];
    { const float dx=fx.x-px, dy=fy.x-py, dz=fz.x-pz; dd[0]=dx*dx+dy*dy+dz*dz; }
    { const float dx=fx.y-px, dy=fy.y-py, dz=fz.y-pz; dd[1]=dx*dx+dy*dy+dz*dz; }
    { const float dx=fx.z-px, dy=fy.z-py, dz=fz.z-pz; dd[2]=dx*dx+dy*dy+dz*dz; }
    { const float dx=fx.w-px, dy=fy.w-py, dz=fz.w-pz; dd[3]=dx*dx+dy*dy+dz*dz; }
    #pragma unroll
    for(int q=0;q<4;++q){
      if (dd[q] < worst){
        d9[wslot]=dd[q]; id9[wslot]=base+q;
        worst=d9[0]; wslot=0;
        #pragma unroll
        for(int k=1;k<9;++k){ if(d9[k]>worst){ worst=d9[k]; wslot=k; } }
      }
    }
  }
  float T = INFINITY;
  for(int r=0;r<9;++r){
    float bv=d9[0]; int bi=id9[0];
    #pragma unroll
    for(int k=1;k<9;++k){
      if (d9[k]<bv || (d9[k]==bv && id9[k]<bi)){ bv=d9[k]; bi=id9[k]; }
    }
    float v=bv; int ix=bi;
    #pragma unroll
    for(int s=32;s>0;s>>=1){
      float ov=__shfl_xor(v,s,64); int oi=__shfl_xor(ix,s,64);
      if (ov<v || (ov==v && oi<ix)){ v=ov; ix=oi; }
    }
    T = v;
    #pragma unroll
    for(int k=0;k<9;++k){
      if (id9[k]==ix){ d9[k]=INFINITY; id9[k]=0x7fffffff; }
    }
  }

  // Phase 2: filter all 8192 candidates by d <= T
  for(int c=0;c<32;++c){
    const int base = (c*64 + lane)*4;
    const float4 fx = *(const float4*)(xs + base);
    const float4 fy = *(const float4*)(ys + base);
    const float4 fz = *(const float4*)(zs + base);
    float dd[4];
    { const float dx=fx.x-px, dy=fy.x-py, dz=fz.x-pz; dd[0]=dx*dx+dy*dy+dz*dz; }
    { const float dx=fx.y-px, dy=fy.y-py, dz=fz.y-pz; dd[1]=dx*dx+dy*dy+dz*dz; }
    { const float dx=fx.z-px, dy=fy.z-py, dz=fz.z-pz; dd[2]=dx*dx+dy*dy+dz*dz; }
    { const float dx=fx.w-px, dy=fy.w-py, dz=fz.w-pz; dd[3]=dx*dx+dy*dy+dz*dz; }
    #pragma unroll
    for(int q=0;q<4;++q){
      if (dd[q] <= T){
        int pos = atomicAdd(&scount[w],1);
        if (pos < KNN_CAP){ sdist[w][pos]=dd[q]; sidx[w][pos]=base+q; }
      }
    }
  }
  __syncthreads();

  // Phase 3: exact top-9 over survivors
  int m = scount[w]; if (m > KNN_CAP) m = KNN_CAP;
  float dl[KNN_CAP/64]; int il[KNN_CAP/64];
  #pragma unroll
  for(int k=0;k<KNN_CAP/64;++k){
    const int j = lane + 64*k;
    if (j < m){ dl[k]=sdist[w][j]; il[k]=sidx[w][j]; }
    else      { dl[k]=INFINITY;    il[k]=0x7fffffff; }
  }
  for(int r=0;r<9;++r){
    float bv=dl[0]; int bi=il[0];
    #pragma unroll
    for(int k=1;k<KNN_CAP/64;++k){
      if (dl[k]<bv || (dl[k]==bv && il[k]<bi)){ bv=dl[k]; bi=il[k]; }
    }
    float v=bv; int ix=bi;
    #pragma unroll
    for(int s=32;s>0;s>>=1){
      float ov=__shfl_xor(v,s,64); int oi=__shfl_xor(ix,s,64);
      if (ov<v || (ov==v && oi<ix)){ v=ov; ix=oi; }
    }
    if (ix != node && lane==0){
      int cpos = atomicAdd(&cnt[ix],1);
      if (cpos < REV_CAP) rev[ix*REV_CAP + cpos] = node;
    }
    #pragma unroll
    for(int k=0;k<KNN_CAP/64;++k){
      if (il[k]==ix){ dl[k]=INFINITY; il[k]=0x7fffffff; }
    }
  }
}

// =================== moment-based message passing: 4 waves/block, 1 node/wave ===================
__global__ __launch_bounds__(256) void k_msg(
  const float* __restrict__ pos,
  const int* __restrict__ cnt, const int* __restrict__ rev,
  const float* __restrict__ Kbuf,
  const float* __restrict__ xf,
  const float* __restrict__ tpw,
  const float* __restrict__ W0, const float* __restrict__ W1, const float* __restrict__ W2,
  float* __restrict__ yf, float* __restrict__ stats)
{
  const int t = threadIdx.x;
  const int w = t >> 6;
  const int lane = t & 63;
  const int n = blockIdx.x*4 + w;
  if (blockIdx.x==0 && t<96) stats[t]=0.f;   // zero stats for this layer (k_stats runs after)

  __shared__ float KL[405];
  __shared__ float TW[144];
  __shared__ float momP[4][120];   // plain moments Σ_e s_c
  __shared__ float momS[4][600];   // sh2 moments Σ_e s_c·sh_j  [c*5+j]
  __shared__ float aS[4][480];     // a0[40] | a1[40*3] | a2[64*5]
  for(int q=t;q<405;q+=256) KL[q]=Kbuf[q];
  for(int q=t;q<144;q+=256) TW[q]=tpw[q];
  __syncthreads();

  // ---- Stage 1: edge loop, accumulate moments (lane owns 2 feature components) ----
  const int deg0 = cnt[n];
  const int deg = (deg0<REV_CAP)? deg0 : REV_CAP;
  const float pnx=pos[3*n], pny=pos[3*n+1], pnz=pos[3*n+2];
  const int c0 = lane*2;
  float mp0=0.f, mp1=0.f;
  float ms0[5], ms1[5];
  #pragma unroll
  for(int j=0;j<5;++j){ ms0[j]=0.f; ms1[j]=0.f; }
  const float s15 = 3.8729833462f, s5c = 2.2360679775f;
  for(int e=0;e<deg;++e){
    const int i = rev[n*REV_CAP+e];
    const float ex = pnx - pos[3*i], ey = pny - pos[3*i+1], ez = pnz - pos[3*i+2];
    const float rn = sqrtf(ex*ex+ey*ey+ez*ez) + 1e-12f;
    const float ux=ex/rn, uy=ey/rn, uz=ez/rn;
    float sh[5];
    sh[0]=s15*ux*uy; sh[1]=s15*uy*uz; sh[2]=0.5f*s5c*(3.f*uz*uz-1.f);
    sh[3]=s15*ux*uz; sh[4]=0.5f*s15*(ux*ux-uy*uy);
    if (lane<60){
      const float2 f = *(const float2*)(xf + (size_t)i*120 + c0);
      mp0 += f.x; mp1 += f.y;
      #pragma unroll
      for(int j=0;j<5;++j){ ms0[j] += f.x*sh[j]; ms1[j] += f.y*sh[j]; }
    }
  }
  if (lane<60){
    momP[w][c0]=mp0; momP[w][c0+1]=mp1;
    #pragma unroll
    for(int j=0;j<5;++j){ momS[w][c0*5+j]=ms0[j]; momS[w][(c0+1)*5+j]=ms1[j]; }
  }
  __syncthreads();

  // ---- Stage 2: per-node K-contraction on moments (same structure as verified per-edge code) ----
  float acc[14];
  #pragma unroll
  for(int k=0;k<14;++k) acc[k]=0.f;

  if (lane<32){
    const int u=lane;
    const float rw0=TW[u], rw1=TW[32+u];
    acc[0] = rw0 * KL[0] * momP[w][u];                       // p1
    float m0s[5];
    #pragma unroll
    for(int j=0;j<5;++j) m0s[j]=momS[w][u*5+j];
    #pragma unroll
    for(int o=0;o<5;++o){ float g=0.f;                       // p2
      #pragma unroll
      for(int j=0;j<5;++j) g += KL[1+o*5+j]*m0s[j];
      acc[1+o] = rw1*g; }
  } else if (lane<48){
    const int u=lane-32;
    const float rw0=TW[64+u], rw1=TW[80+u], rw2=TW[96+u];
    float m1p[3], m1s[3][5];
    #pragma unroll
    for(int i=0;i<3;++i){
      m1p[i]=momP[w][32+u*3+i];
      #pragma unroll
      for(int j=0;j<5;++j) m1s[i][j]=momS[w][(32+u*3+i)*5+j];
    }
    #pragma unroll
    for(int o=0;o<3;++o){ float g=0.f;                       // p3
      #pragma unroll
      for(int i=0;i<3;++i) g += KL[26+o*3+i]*m1p[i];
      acc[o]=rw0*g; }
    #pragma unroll
    for(int o=0;o<3;++o){ float g=0.f;                       // p4
      #pragma unroll
      for(int i=0;i<3;++i)
        #pragma unroll
        for(int j=0;j<5;++j) g += KL[35+(o*3+i)*5+j]*m1s[i][j];
      acc[3+o]=rw1*g; }
    #pragma unroll
    for(int o=0;o<5;++o){ float g=0.f;                       // p5
      #pragma unroll
      for(int i=0;i<3;++i)
        #pragma unroll
        for(int j=0;j<5;++j) g += KL[80+(o*3+i)*5+j]*m1s[i][j];
      acc[6+o]=rw2*g; }
  } else if (lane<56){
    const int u=lane-48;
    const float rw0=TW[112+u], rw1=TW[120+u], rw2=TW[128+u], rw3=TW[136+u];
    float m2p[5], m2s[5][5];
    #pragma unroll
    for(int i=0;i<5;++i){
      m2p[i]=momP[w][80+u*5+i];
      #pragma unroll
      for(int j=0;j<5;++j) m2s[i][j]=momS[w][(80+u*5+i)*5+j];
    }
    #pragma unroll
    for(int o=0;o<5;++o){ float g=0.f;                       // p6
      #pragma unroll
      for(int i=0;i<5;++i) g += KL[155+o*5+i]*m2p[i];
      acc[o]=rw0*g; }
    { float g=0.f;                                           // p7
      #pragma unroll
      for(int i=0;i<5;++i)
        #pragma unroll
        for(int j=0;j<5;++j) g += KL[180+i*5+j]*m2s[i][j];
      acc[5]=rw1*g; }
    #pragma unroll
    for(int o=0;o<3;++o){ float g=0.f;                       // p8
      #pragma unroll
      for(int i=0;i<5;++i)
        #pragma unroll
        for(int j=0;j<5;++j) g += KL[205+(o*5+i)*5+j]*m2s[i][j];
      acc[6+o]=rw2*g; }
    #pragma unroll
    for(int o=0;o<5;++o){ float g=0.f;                       // p9
      #pragma unroll
      for(int i=0;i<5;++i)
        #pragma unroll
        for(int j=0;j<5;++j) g += KL[280+(o*5+i)*5+j]*m2s[i][j];
      acc[9+o]=rw3*g; }
  }

  // scatter accumulators into aS: concat orders m0=[p1,p7], m1=[p3,p4,p8], m2=[p2,p5,p6,p9]
  if (lane<32){
    aS[w][lane] = acc[0];
    #pragma unroll
    for(int o=0;o<5;++o) aS[w][160 + lane*5+o] = acc[1+o];
  } else if (lane<48){
    const int uu=lane-32;
    #pragma unroll
    for(int m=0;m<3;++m){ aS[w][40 + uu*3+m] = acc[m]; aS[w][40 + (16+uu)*3+m] = acc[3+m]; }
    #pragma unroll
    for(int o=0;o<5;++o) aS[w][160 + (32+uu)*5+o] = acc[6+o];
  } else if (lane<56){
    const int uu=lane-48;
    aS[w][32+uu] = acc[5];
    #pragma unroll
    for(int m=0;m<3;++m) aS[w][40 + (32+uu)*3+m] = acc[6+m];
    #pragma unroll
    for(int o=0;o<5;++o){ aS[w][160 + (48+uu)*5+o] = acc[o]; aS[w][160 + (56+uu)*5+o] = acc[9+o]; }
  }
  __syncthreads();

  // ---- Stage 3: linear mixes, write yf[n][120] ----
  const float inv40 = 0.15811388300841896660f;
  for(int q=lane;q<120;q+=64){
    float out;
    if (q<32){
      float g=0.f;
      for(int uu=0;uu<40;++uu) g += aS[w][uu]*W0[uu*32+q];
      out = g*inv40;
    } else if (q<80){
      const int e=q-32, v=e/3, m=e%3;
      float g=0.f;
      for(int uu=0;uu<40;++uu) g += aS[w][40+uu*3+m]*W1[uu*16+v];
      out = g*inv40;
    } else {
      const int e=q-80, tt=e/5, m=e%5;
      float g=0.f;
      for(int uu=0;uu<64;++uu) g += aS[w][160+uu*5+m]*W2[uu*8+tt];
      out = g*0.125f;
    }
    yf[(size_t)n*120+q] = out;
  }
}

// =================== per-channel global stats: 96 ch x 8 chunks, atomic accumulate ===================
__global__ __launch_bounds__(256) void k_stats(const float* __restrict__ yf,
                                               float* __restrict__ stats){
  const int ch = blockIdx.x % 96;
  const int chunk = blockIdx.x / 96;
  const int t = threadIdx.x;
  const int n0 = chunk*1024;
  __shared__ float r1[256], r2[256];
  float a1=0.f, a2=0.f;
  if (ch<32){
    for(int nn=t;nn<1024;nn+=256){ float v=yf[(size_t)(n0+nn)*120+ch]; a1+=v; a2+=v*v; }
  } else if (ch<48){
    const int v_=ch-32;
    for(int nn=t;nn<1024;nn+=256){
      #pragma unroll
      for(int m=0;m<3;++m){ float v=yf[(size_t)(n0+nn)*120+32+v_*3+m]; a2+=v*v; }
    }
  } else {
    const int t_=ch-48;
    for(int nn=t;nn<1024;nn+=256){
      #pragma unroll
      for(int m=0;m<5;++m){ float v=yf[(size_t)(n0+nn)*120+80+t_*5+m]; a2+=v*v; }
    }
  }
  r1[t]=a1; r2[t]=a2; __syncthreads();
  for(int s=128;s>0;s>>=1){ if(t<s){ r1[t]+=r1[t+s]; r2[t]+=r2[t+s]; } __syncthreads(); }
  if(t==0){
    if(ch<32){ atomicAdd(&stats[ch], r1[0]); atomicAdd(&stats[32+ch], r2[0]); }
    else if(ch<48) atomicAdd(&stats[64+(ch-32)], r2[0]);
    else atomicAdd(&stats[80+(ch-48)], r2[0]);
  }
}

// =================== normalize + relu + residual (coalesced on [n][120]) ===================
__global__ void k_norm(const float* __restrict__ yf, const float* __restrict__ stats,
                       const float* __restrict__ bw0,const float* __restrict__ bb0,
                       const float* __restrict__ bw1,const float* __restrict__ bw2,
                       float* __restrict__ xf){
  const int idx = blockIdx.x*256 + threadIdx.x;
  if (idx >= NN*120) return;
  const int c = idx%120;
  const float yv = yf[idx];
  float v;
  if (c<32){
    const float mean = stats[c]*(1.f/8192.f);
    const float var  = stats[32+c]*(1.f/8192.f) - mean*mean;
    v = (yv-mean)/sqrtf(var+1e-5f)*bw0[c]+bb0[c];
  } else if (c<80){
    const int e=c-32, v_=e/3;
    v = yv/sqrtf(stats[64+v_]*(1.f/(8192.f*3.f))+1e-5f)*bw1[v_];
  } else {
    const int e=c-80, t_=e/5;
    v = yv/sqrtf(stats[80+t_]*(1.f/(8192.f*5.f))+1e-5f)*bw2[t_];
  }
  xf[idx] += fmaxf(v,0.f);
}

// =================== final MLP ===================
__global__ __launch_bounds__(256) void k_mlp(const float* __restrict__ xf,
                                             const float* __restrict__ Wf1,const float* __restrict__ Wf2,
                                             const float* __restrict__ bf2,const float* __restrict__ Wf3,
                                             const float* __restrict__ bf3, float* __restrict__ out){
  __shared__ float w1[1024], w2[512], w3[32], b2[16], b3[2];
  const int t=threadIdx.x;
  for(int q=t;q<1024;q+=256) w1[q]=Wf1[q];
  for(int q=t;q<512;q+=256)  w2[q]=Wf2[q];
  if(t<32) w3[t]=Wf3[t];
  if(t<16) b2[t]=bf2[t];
  if(t<2)  b3[t]=bf3[t];
  __syncthreads();
  const int n = blockIdx.x*256+t;
  if(n>=NN) return;
  float xv[32];
  #pragma unroll
  for(int k=0;k<32;++k) xv[k]=xf[(size_t)n*120+k];
  const float inv32 = 0.17677669529663688110f;
  float h1[32];
  #pragma unroll 4
  for(int c=0;c<32;++c){ float g=0.f;
    #pragma unroll
    for(int k=0;k<32;++k) g+=xv[k]*w1[k*32+c];
    h1[c]=fmaxf(g*inv32,0.f); }
  float h2[16];
  #pragma unroll 4
  for(int c=0;c<16;++c){ float g=b2[c];
    #pragma unroll
    for(int k=0;k<32;++k) g+=h1[k]*w2[k*16+c];
    h2[c]=fmaxf(g,0.f); }
  #pragma unroll
  for(int m=0;m<2;++m){ float g=b3[m];
    #pragma unroll
    for(int k=0;k<16;++k) g+=h2[k]*w3[k*2+m];
    out[n*2+m]=g; }
}

extern "C" void kernel_launch(void* const* d_in, const int* in_sizes, int n_in,
                              void* d_out, int out_size, void* d_ws, size_t ws_size,
                              hipStream_t stream) {
  const float* positions = (const float*)d_in[0];
  const float* W_emb  = (const float*)d_in[1];
  const float* tp_w   = (const float*)d_in[2];
  const float* lin_W0 = (const float*)d_in[3];
  const float* lin_W1 = (const float*)d_in[4];
  const float* lin_W2 = (const float*)d_in[5];
  const float* bn_w0  = (const float*)d_in[6];
  const float* bn_b0  = (const float*)d_in[7];
  const float* bn_w1  = (const float*)d_in[8];
  const float* bn_w2  = (const float*)d_in[9];
  const float* Wf1 = (const float*)d_in[10];
  const float* Wf2 = (const float*)d_in[11];
  const float* bf2 = (const float*)d_in[12];
  const float* Wf3 = (const float*)d_in[13];
  const float* bf3 = (const float*)d_in[14];

  if (ws_size < WS_FLOATS*sizeof(float)) return;

  float* ws    = (float*)d_ws;
  float* Kbuf  = ws + OFF_K;
  float* stats = ws + OFF_STATS;
  int*   cnt   = (int*)(ws + OFF_CNT);
  int*   rev   = (int*)(ws + OFF_REV);
  float* xf = ws + OFF_XF;
  float* yf = ws + OFF_YF;

  // SoA position arrays alias the head of yf (dead after k_knn3; first k_msg rewrites all of yf)
  float* xs = yf;
  float* ysA = yf + NN;
  float* zs = yf + 2*NN;

  k_setup<<<3906,256,0,stream>>>(positions, W_emb, Kbuf, xf, xs, ysA, zs, cnt);
  k_knn3<<<NN/4,256,0,stream>>>(xs, ysA, zs, cnt, rev);

  for(int l=0;l<3;++l){
    k_msg<<<NN/4,256,0,stream>>>(positions, cnt, rev, Kbuf, xf,
                              tp_w + l*144, lin_W0 + l*40*32, lin_W1 + l*40*16, lin_W2 + l*64*8,
                              yf, stats);
    k_stats<<<768,256,0,stream>>>(yf,stats);
    k_norm<<<(NN*120+255)/256,256,0,stream>>>(yf,stats,
                              bn_w0 + l*32, bn_b0 + l*32, bn_w1 + l*16, bn_w2 + l*8,
                              xf);
  }
  k_mlp<<<NN/256,256,0,stream>>>(xf,Wf1,Wf2,bf2,Wf3,bf3,(float*)d_out);
}